// Round 1
// baseline (584.005 us; speedup 1.0000x reference)
//
#include <hip/hip_runtime.h>
#include <hip/hip_bf16.h>

#define B_ 4
#define L_ 2048
#define DM 1024
#define DI 2048
#define NR (B_ * L_)   // 8192 rows
#define DTR 64
#define NCHUNK 16
#define CHUNK 128

typedef __attribute__((ext_vector_type(8))) short short8;
typedef __attribute__((ext_vector_type(4))) float floatx4;

// ---------------- workspace layout (bytes) ----------------
static constexpr size_t OFF_SCAL = 0;                                    // 4 f32 scales
static constexpr size_t OFF_PART = 256;                                  // 4*256 f32 partials
static constexpr size_t OFF_XN   = 4608;                                 // xn bf16 [NR,DM]
static constexpr size_t OFF_TIN  = OFF_XN   + (size_t)NR * DM * 2;       // T_in bf16 [4096,1024]
static constexpr size_t OFF_TX   = OFF_TIN  + (size_t)2 * DI * DM * 2;   // T_x bf16 [64,2048]
static constexpr size_t OFF_TDT  = OFF_TX   + (size_t)DTR * DI * 2;      // T_dt bf16 [2048,64]
static constexpr size_t OFF_TOUT = OFF_TDT  + (size_t)DI * DTR * 2;      // T_out bf16 [1024,2048]
static constexpr size_t OFF_XC   = OFF_TOUT + (size_t)DM * DI * 2;       // xc f32 [NR,DI]
static constexpr size_t OFF_ZSP  = OFF_XC   + (size_t)NR * DI * 4;       // sp(z) bf16 [NR,DI]
static constexpr size_t OFF_XACT = OFF_ZSP  + (size_t)NR * DI * 2;       // sp(conv) bf16 [NR,DI]
static constexpr size_t OFF_DBL  = OFF_XACT + (size_t)NR * DI * 2;       // dbl bf16 [NR,64]
static constexpr size_t OFF_DEC  = OFF_DBL  + (size_t)NR * DTR * 2;      // decay u16 [NR,DI]
static constexpr size_t OFF_CA   = OFF_DEC  + (size_t)NR * DI * 2;       // chunk A f32 [B,16,DI]
static constexpr size_t OFF_CB   = OFF_CA   + (size_t)B_ * NCHUNK * DI * 4;
static constexpr size_t OFF_PRE  = OFF_CB   + (size_t)B_ * NCHUNK * DI * 4;
static constexpr size_t OFF_Y    = OFF_PRE  + (size_t)B_ * NCHUNK * DI * 4; // y bf16 [NR,DI]

// ---------------- scalar math (bit-faithful to reference) ----------------
__device__ __forceinline__ float pow2scale(float var) {
    float v = var + 1e-9f;
    float s = 1.0f;
    if (v >= 4.0f)     s = 0.5f;
    if (v >= 16.0f)    s = 0.25f;
    if (v >= 64.0f)    s = 0.125f;
    if (v >= 256.0f)   s = 0.0625f;
    if (v >= 1024.0f)  s = 0.03125f;
    if (v >= 4096.0f)  s = 0.015625f;
    if (v >= 16384.0f) s = 0.0078125f;
    if (v >= 65536.0f) s = 0.00390625f;
    if (v < 1.0f)    s = 1.0f;
    if (v < 0.25f)   s = 2.0f;
    if (v < 0.0625f) s = 4.0f;
    return s;
}

__device__ __forceinline__ float squareplus_f(float x) {
    float y = fminf(fmaxf(x * x + 4.0f, 1e-6f), 1e6f);
    // _rsqrt_newton (y already in [1e-6,1e6])
    float r = (y > 16.0f) ? 0.125f : 0.5f;
    if (y > 64.0f)  r = 0.0625f;
    if (y > 256.0f) r = 0.03125f;
    if (y < 4.0f)   r = 1.0f;
    if (y < 1.0f)   r = 2.0f;
    if (y < 0.25f)  r = 4.0f;
#pragma unroll
    for (int i = 0; i < 3; ++i) {
        r = r * (1.5f - 0.5f * y * r * r);
        r = fminf(fmaxf(r, 1e-6f), 1e3f);
    }
    float s = fminf(fmaxf(y * r, 0.0f), 1e3f);
    return 0.5f * (x + s);
}

__device__ __forceinline__ float block_reduce_sum(float v) {
    __shared__ float sm[4];
#pragma unroll
    for (int o = 32; o > 0; o >>= 1) v += __shfl_down(v, o, 64);
    int w = threadIdx.x >> 6;
    __syncthreads();
    if ((threadIdx.x & 63) == 0) sm[w] = v;
    __syncthreads();
    return (sm[0] + sm[1]) + (sm[2] + sm[3]);
}

// ---------------- weight-scale reduction + ternary quantization ----------------
__global__ __launch_bounds__(256) void k_abs_partial(const float* __restrict__ W, int n,
                                                     float* __restrict__ part) {
    float s = 0.f;
    for (int i = blockIdx.x * 256 + threadIdx.x; i < n; i += 256 * gridDim.x)
        s += fabsf(W[i]);
    float t = block_reduce_sum(s);
    if (threadIdx.x == 0) part[blockIdx.x] = t;
}

__global__ __launch_bounds__(256) void k_finalize(const float* __restrict__ part,
                                                  float* __restrict__ scal) {
    const float counts[4] = {(float)(2 * DI * DM), (float)(96 * DI),
                             (float)(DI * DTR), (float)(DM * DI)};
    for (int w = 0; w < 4; ++w) {
        float s = block_reduce_sum(part[w * 256 + threadIdx.x]);
        if (threadIdx.x == 0) scal[w] = s / counts[w] + 1e-8f;
    }
}

__global__ __launch_bounds__(256) void k_quant(const float* __restrict__ W,
                                               const float* __restrict__ s_ptr,
                                               __hip_bfloat16* __restrict__ T) {
    int i = blockIdx.x * 256 + threadIdx.x;
    float s = *s_ptr;
    float q = rintf(W[i] / s);
    q = fmaxf(-1.0f, fminf(1.0f, q));
    T[i] = __float2bfloat16(q);
}

// ---------------- bitshift_norm ----------------
__global__ __launch_bounds__(256) void k_norm(const float* __restrict__ x,
                                              const float* __restrict__ gamma,
                                              const float* __restrict__ step,
                                              __hip_bfloat16* __restrict__ xn) {
    int row = blockIdx.x;
    const float* xr = x + (size_t)row * DM;
    float s = 0.f;
    for (int i = threadIdx.x; i < DM; i += 256) s += xr[i];
    float mean = block_reduce_sum(s) * (1.0f / DM);
    float v = 0.f;
    for (int i = threadIdx.x; i < DM; i += 256) { float d = xr[i] - mean; v += d * d; }
    float var = block_reduce_sum(v) * (1.0f / DM);
    float sc = pow2scale(var);
    float st = step[0];
    for (int i = threadIdx.x; i < DM; i += 256) {
        float val = ((xr[i] - mean) * sc) * gamma[i] * st;
        xn[(size_t)row * DM + i] = __float2bfloat16(val);
    }
}

// ---------------- MFMA GEMM: C = A[M,K] @ B[N,K]^T, bf16 in, f32 acc ----------------
// MODE 0: xz epilogue  (col<DI -> xc f32 ; col>=DI -> bf16 squareplus(z))
// MODE 1: plain bf16 out
// MODE 2: dt -> sigmoid -> dyadic u16 decay
// MODE 3: f32 out + residual
template <int BM, int BN, int WR, int WC, int MODE>
__global__ __launch_bounds__(256) void k_gemm(
    const __hip_bfloat16* __restrict__ A, const __hip_bfloat16* __restrict__ Bw,
    int M, int N, int K, const float* __restrict__ s_ptr,
    float* __restrict__ o_f32, __hip_bfloat16* __restrict__ o_bf16,
    unsigned short* __restrict__ o_u16,
    const float* __restrict__ bias, const float* __restrict__ resid) {
    constexpr int BK = 32, LDA = BK + 8;
    constexpr int FM = BM / (WR * 16), FN = BN / (WC * 16);
    __shared__ __align__(16) short lA[BM * LDA];
    __shared__ __align__(16) short lB[BN * LDA];
    const int tid = threadIdx.x;
    const int lane = tid & 63, wid = tid >> 6;
    const int wm = (wid / WC) * (BM / WR);
    const int wn = (wid % WC) * (BN / WC);
    const int r16 = lane & 15, quad = lane >> 4;
    const int m0 = blockIdx.y * BM, n0 = blockIdx.x * BN;

    floatx4 acc[FM][FN] = {};

    for (int k0 = 0; k0 < K; k0 += BK) {
        __syncthreads();
#pragma unroll
        for (int c = tid; c < BM * BK / 8; c += 256) {
            int row = c >> 2, kc = (c & 3) << 3;
            *reinterpret_cast<ulonglong2*>(&lA[row * LDA + kc]) =
                *reinterpret_cast<const ulonglong2*>(&A[(size_t)(m0 + row) * K + k0 + kc]);
        }
#pragma unroll
        for (int c = tid; c < BN * BK / 8; c += 256) {
            int row = c >> 2, kc = (c & 3) << 3;
            *reinterpret_cast<ulonglong2*>(&lB[row * LDA + kc]) =
                *reinterpret_cast<const ulonglong2*>(&Bw[(size_t)(n0 + row) * K + k0 + kc]);
        }
        __syncthreads();
        short8 af[FM], bfv[FN];
#pragma unroll
        for (int i = 0; i < FM; ++i)
            af[i] = *reinterpret_cast<const short8*>(&lA[(wm + i * 16 + r16) * LDA + quad * 8]);
#pragma unroll
        for (int j = 0; j < FN; ++j)
            bfv[j] = *reinterpret_cast<const short8*>(&lB[(wn + j * 16 + r16) * LDA + quad * 8]);
#pragma unroll
        for (int i = 0; i < FM; ++i)
#pragma unroll
            for (int j = 0; j < FN; ++j)
                acc[i][j] = __builtin_amdgcn_mfma_f32_16x16x32_bf16(af[i], bfv[j], acc[i][j], 0, 0, 0);
    }

    const float s = *s_ptr;
#pragma unroll
    for (int i = 0; i < FM; ++i) {
#pragma unroll
        for (int j = 0; j < FN; ++j) {
#pragma unroll
            for (int r = 0; r < 4; ++r) {
                int gr = m0 + wm + i * 16 + quad * 4 + r;
                int gc = n0 + wn + j * 16 + r16;
                float v = acc[i][j][r] * s;
                if (MODE == 0) {
                    if (gc < DI) o_f32[(size_t)gr * DI + gc] = v;
                    else o_bf16[(size_t)gr * DI + (gc - DI)] = __float2bfloat16(squareplus_f(v));
                } else if (MODE == 1) {
                    o_bf16[(size_t)gr * N + gc] = __float2bfloat16(v);
                } else if (MODE == 2) {
                    float dt = v + bias[gc];
                    float dc = 0.5f + 0.5f * dt / (1.0f + fabsf(dt));
                    o_u16[(size_t)gr * N + gc] = (unsigned short)rintf(dc * 32768.0f);
                } else {
                    o_f32[(size_t)gr * N + gc] = v + resid[(size_t)gr * N + gc];
                }
            }
        }
    }
}

// ---------------- causal depthwise conv (k=4) + bias + squareplus ----------------
__global__ __launch_bounds__(256) void k_conv(const float* __restrict__ xc,
                                              const float* __restrict__ cw,
                                              const float* __restrict__ cb,
                                              __hip_bfloat16* __restrict__ xact) {
    int c = blockIdx.x * 256 + threadIdx.x;
    int t0 = blockIdx.y * CHUNK;
    int b = blockIdx.z;
    float w0 = cw[c * 4 + 0], w1 = cw[c * 4 + 1], w2 = cw[c * 4 + 2], w3 = cw[c * 4 + 3];
    float bias = cb[c];
    const float* base = xc + (size_t)b * L_ * DI + c;
    float x3 = (t0 - 3 >= 0) ? base[(size_t)(t0 - 3) * DI] : 0.f;
    float x2 = (t0 - 2 >= 0) ? base[(size_t)(t0 - 2) * DI] : 0.f;
    float x1 = (t0 - 1 >= 0) ? base[(size_t)(t0 - 1) * DI] : 0.f;
    for (int t = t0; t < t0 + CHUNK; ++t) {
        float xt = base[(size_t)t * DI];
        float y = x3 * w0 + x2 * w1 + x1 * w2 + xt * w3 + bias;
        xact[((size_t)(b * L_ + t)) * DI + c] = __float2bfloat16(squareplus_f(y));
        x3 = x2; x2 = x1; x1 = xt;
    }
}

// ---------------- 3-pass chunked linear scan ----------------
__global__ __launch_bounds__(256) void k_scan1(const unsigned short* __restrict__ dk,
                                               const __hip_bfloat16* __restrict__ u,
                                               float* __restrict__ cA, float* __restrict__ cB) {
    int c = blockIdx.x * 256 + threadIdx.x;
    int j = blockIdx.y, b = blockIdx.z;
    size_t base = ((size_t)b * L_ + (size_t)j * CHUNK) * DI + c;
    float Ac = 1.f, Bc = 0.f;
    for (int t = 0; t < CHUNK; ++t) {
        float a = dk[base + (size_t)t * DI] * (1.0f / 32768.0f);
        float uv = __bfloat162float(u[base + (size_t)t * DI]);
        Bc = a * Bc + (1.f - a) * uv;
        Ac *= a;
    }
    size_t o = ((size_t)(b * NCHUNK + j)) * DI + c;
    cA[o] = Ac;
    cB[o] = Bc;
}

__global__ __launch_bounds__(256) void k_scan2(const float* __restrict__ cA,
                                               const float* __restrict__ cB,
                                               float* __restrict__ pre) {
    int idx = blockIdx.x * 256 + threadIdx.x;  // b*DI + c
    int b = idx >> 11, c = idx & (DI - 1);
    float h = 0.f;
    for (int j = 0; j < NCHUNK; ++j) {
        size_t o = ((size_t)(b * NCHUNK + j)) * DI + c;
        pre[o] = h;
        h = cA[o] * h + cB[o];
    }
}

__global__ __launch_bounds__(256) void k_scan3(const unsigned short* __restrict__ dk,
                                               const __hip_bfloat16* __restrict__ u,
                                               const __hip_bfloat16* __restrict__ zsp,
                                               const float* __restrict__ pre,
                                               __hip_bfloat16* __restrict__ y) {
    int c = blockIdx.x * 256 + threadIdx.x;
    int j = blockIdx.y, b = blockIdx.z;
    size_t base = ((size_t)b * L_ + (size_t)j * CHUNK) * DI + c;
    float h = pre[((size_t)(b * NCHUNK + j)) * DI + c];
    for (int t = 0; t < CHUNK; ++t) {
        float a = dk[base + (size_t)t * DI] * (1.0f / 32768.0f);
        float uv = __bfloat162float(u[base + (size_t)t * DI]);
        h = a * h + (1.f - a) * uv;
        float yv = h * __bfloat162float(zsp[base + (size_t)t * DI]);
        y[base + (size_t)t * DI] = __float2bfloat16(yv);
    }
}

// ---------------- launch ----------------
extern "C" void kernel_launch(void* const* d_in, const int* in_sizes, int n_in,
                              void* d_out, int out_size, void* d_ws, size_t ws_size,
                              hipStream_t stream) {
    const float* x      = (const float*)d_in[0];
    const float* gamma  = (const float*)d_in[1];
    const float* step   = (const float*)d_in[2];
    const float* W_in   = (const float*)d_in[3];
    const float* conv_w = (const float*)d_in[4];
    const float* conv_b = (const float*)d_in[5];
    const float* W_x    = (const float*)d_in[6];
    const float* W_dt   = (const float*)d_in[7];
    const float* b_dt   = (const float*)d_in[8];
    const float* W_out  = (const float*)d_in[9];

    char* ws = (char*)d_ws;
    float*          scal = (float*)(ws + OFF_SCAL);
    float*          part = (float*)(ws + OFF_PART);
    __hip_bfloat16* xn   = (__hip_bfloat16*)(ws + OFF_XN);
    __hip_bfloat16* Tin  = (__hip_bfloat16*)(ws + OFF_TIN);
    __hip_bfloat16* Tx   = (__hip_bfloat16*)(ws + OFF_TX);
    __hip_bfloat16* Tdt  = (__hip_bfloat16*)(ws + OFF_TDT);
    __hip_bfloat16* Tout = (__hip_bfloat16*)(ws + OFF_TOUT);
    float*          xcf  = (float*)(ws + OFF_XC);
    __hip_bfloat16* zsp  = (__hip_bfloat16*)(ws + OFF_ZSP);
    __hip_bfloat16* xact = (__hip_bfloat16*)(ws + OFF_XACT);
    __hip_bfloat16* dbl  = (__hip_bfloat16*)(ws + OFF_DBL);
    unsigned short* dec  = (unsigned short*)(ws + OFF_DEC);
    float*          cA   = (float*)(ws + OFF_CA);
    float*          cB   = (float*)(ws + OFF_CB);
    float*          pre  = (float*)(ws + OFF_PRE);
    __hip_bfloat16* yb   = (__hip_bfloat16*)(ws + OFF_Y);
    float*          out  = (float*)d_out;

    // weight scales (deterministic two-stage reductions) + ternary quantization
    k_abs_partial<<<256, 256, 0, stream>>>(W_in, 2 * DI * DM, part + 0 * 256);
    k_abs_partial<<<256, 256, 0, stream>>>(W_x, 96 * DI, part + 1 * 256);
    k_abs_partial<<<256, 256, 0, stream>>>(W_dt, DI * DTR, part + 2 * 256);
    k_abs_partial<<<256, 256, 0, stream>>>(W_out, DM * DI, part + 3 * 256);
    k_finalize<<<1, 256, 0, stream>>>(part, scal);
    k_quant<<<(2 * DI * DM) / 256, 256, 0, stream>>>(W_in, scal + 0, Tin);
    k_quant<<<(DTR * DI) / 256, 256, 0, stream>>>(W_x, scal + 1, Tx);     // only first 64 rows used
    k_quant<<<(DI * DTR) / 256, 256, 0, stream>>>(W_dt, scal + 2, Tdt);
    k_quant<<<(DM * DI) / 256, 256, 0, stream>>>(W_out, scal + 3, Tout);

    // norm -> xn (bf16)
    k_norm<<<NR, 256, 0, stream>>>(x, gamma, step, xn);

    // GEMM1: xz = xn @ T_in^T * s ; split -> xc f32, sp(z) bf16
    k_gemm<128, 128, 2, 2, 0><<<dim3((2 * DI) / 128, NR / 128), 256, 0, stream>>>(
        xn, Tin, NR, 2 * DI, DM, scal + 0, xcf, zsp, nullptr, nullptr, nullptr);

    // conv + bias + squareplus -> xact (bf16)
    k_conv<<<dim3(DI / 256, L_ / CHUNK, B_), 256, 0, stream>>>(xcf, conv_w, conv_b, xact);

    // GEMM2: dbl = xact @ T_x[:64]^T * s  -> bf16 [NR,64]
    k_gemm<128, 64, 4, 1, 1><<<dim3(1, NR / 128), 256, 0, stream>>>(
        xact, Tx, NR, DTR, DI, scal + 1, nullptr, dbl, nullptr, nullptr, nullptr);

    // GEMM3: dt = dbl @ T_dt^T * s + b_dt -> sigmoid -> dyadic u16 decay
    k_gemm<128, 128, 2, 2, 2><<<dim3(DI / 128, NR / 128), 256, 0, stream>>>(
        dbl, Tdt, NR, DI, DTR, scal + 2, nullptr, nullptr, dec, b_dt, nullptr);

    // scan (3 passes), pass3 fuses y = h * sp(z) -> bf16
    k_scan1<<<dim3(DI / 256, NCHUNK, B_), 256, 0, stream>>>(dec, xact, cA, cB);
    k_scan2<<<(B_ * DI) / 256, 256, 0, stream>>>(cA, cB, pre);
    k_scan3<<<dim3(DI / 256, NCHUNK, B_), 256, 0, stream>>>(dec, xact, zsp, pre, yb);

    // GEMM4: out = y @ T_out^T * s + residual
    k_gemm<128, 128, 2, 2, 3><<<dim3(DM / 128, NR / 128), 256, 0, stream>>>(
        yb, Tout, NR, DM, DI, scal + 3, out, nullptr, nullptr, nullptr, x);

    (void)in_sizes; (void)n_in; (void)out_size; (void)ws_size;
}

// Round 2
// 485.841 us; speedup vs baseline: 1.2020x; 1.2020x over previous
//
#include <hip/hip_runtime.h>
#include <hip/hip_bf16.h>

#define B_ 4
#define L_ 2048
#define DM 1024
#define DI 2048
#define NR (B_ * L_)   // 8192 rows
#define DTR 64
#define NCHUNK 16
#define CHUNK 128

typedef __attribute__((ext_vector_type(8))) short short8;
typedef __attribute__((ext_vector_type(4))) float floatx4;

// ---------------- workspace layout (bytes) ----------------
static constexpr size_t OFF_SCAL = 0;                                    // 4 f32 scales
static constexpr size_t OFF_PART = 256;                                  // 4*256 f32 partials
static constexpr size_t OFF_XN   = 4608;                                 // xn bf16 [NR,DM]
static constexpr size_t OFF_TIN  = OFF_XN   + (size_t)NR * DM * 2;       // T_in bf16 [4096,1024]
static constexpr size_t OFF_TX   = OFF_TIN  + (size_t)2 * DI * DM * 2;   // T_x bf16 [64,2048]
static constexpr size_t OFF_TDT  = OFF_TX   + (size_t)DTR * DI * 2;      // T_dt bf16 [2048,64]
static constexpr size_t OFF_TOUT = OFF_TDT  + (size_t)DI * DTR * 2;      // T_out bf16 [1024,2048]
static constexpr size_t OFF_XC   = OFF_TOUT + (size_t)DM * DI * 2;       // xc f32 [NR,DI]
static constexpr size_t OFF_ZSP  = OFF_XC   + (size_t)NR * DI * 4;       // sp(z) bf16 [NR,DI]
static constexpr size_t OFF_XACT = OFF_ZSP  + (size_t)NR * DI * 2;       // sp(conv) bf16 [NR,DI]
static constexpr size_t OFF_DBL  = OFF_XACT + (size_t)NR * DI * 2;       // dbl bf16 [NR,64]
static constexpr size_t OFF_DEC  = OFF_DBL  + (size_t)NR * DTR * 2;      // decay u16 [NR,DI]
static constexpr size_t OFF_CA   = OFF_DEC  + (size_t)NR * DI * 2;       // chunk A f32 [B,16,DI]
static constexpr size_t OFF_CB   = OFF_CA   + (size_t)B_ * NCHUNK * DI * 4;
static constexpr size_t OFF_PRE  = OFF_CB   + (size_t)B_ * NCHUNK * DI * 4;
static constexpr size_t OFF_Y    = OFF_PRE  + (size_t)B_ * NCHUNK * DI * 4; // y bf16 [NR,DI]

// ---------------- async global->LDS (16B per lane, wave-uniform base rule) ----------------
__device__ __forceinline__ void async16(const void* g, void* l) {
    __builtin_amdgcn_global_load_lds(
        (const __attribute__((address_space(1))) unsigned int*)g,
        (__attribute__((address_space(3))) unsigned int*)l, 16, 0, 0);
}

// ---------------- scalar math (bit-faithful to reference) ----------------
__device__ __forceinline__ float pow2scale(float var) {
    float v = var + 1e-9f;
    float s = 1.0f;
    if (v >= 4.0f)     s = 0.5f;
    if (v >= 16.0f)    s = 0.25f;
    if (v >= 64.0f)    s = 0.125f;
    if (v >= 256.0f)   s = 0.0625f;
    if (v >= 1024.0f)  s = 0.03125f;
    if (v >= 4096.0f)  s = 0.015625f;
    if (v >= 16384.0f) s = 0.0078125f;
    if (v >= 65536.0f) s = 0.00390625f;
    if (v < 1.0f)    s = 1.0f;
    if (v < 0.25f)   s = 2.0f;
    if (v < 0.0625f) s = 4.0f;
    return s;
}

__device__ __forceinline__ float squareplus_f(float x) {
    float y = fminf(fmaxf(x * x + 4.0f, 1e-6f), 1e6f);
    float r = (y > 16.0f) ? 0.125f : 0.5f;
    if (y > 64.0f)  r = 0.0625f;
    if (y > 256.0f) r = 0.03125f;
    if (y < 4.0f)   r = 1.0f;
    if (y < 1.0f)   r = 2.0f;
    if (y < 0.25f)  r = 4.0f;
#pragma unroll
    for (int i = 0; i < 3; ++i) {
        r = r * (1.5f - 0.5f * y * r * r);
        r = fminf(fmaxf(r, 1e-6f), 1e3f);
    }
    float s = fminf(fmaxf(y * r, 0.0f), 1e3f);
    return 0.5f * (x + s);
}

__device__ __forceinline__ float block_reduce_sum(float v) {
    __shared__ float sm[4];
#pragma unroll
    for (int o = 32; o > 0; o >>= 1) v += __shfl_down(v, o, 64);
    int w = threadIdx.x >> 6;
    __syncthreads();
    if ((threadIdx.x & 63) == 0) sm[w] = v;
    __syncthreads();
    return (sm[0] + sm[1]) + (sm[2] + sm[3]);
}

// ---------------- weight-scale reduction + ternary quantization ----------------
__global__ __launch_bounds__(256) void k_abs_partial(const float* __restrict__ W, int n,
                                                     float* __restrict__ part) {
    float s = 0.f;
    for (int i = blockIdx.x * 256 + threadIdx.x; i < n; i += 256 * gridDim.x)
        s += fabsf(W[i]);
    float t = block_reduce_sum(s);
    if (threadIdx.x == 0) part[blockIdx.x] = t;
}

__global__ __launch_bounds__(256) void k_finalize(const float* __restrict__ part,
                                                  float* __restrict__ scal) {
    const float counts[4] = {(float)(2 * DI * DM), (float)(96 * DI),
                             (float)(DI * DTR), (float)(DM * DI)};
    for (int w = 0; w < 4; ++w) {
        float s = block_reduce_sum(part[w * 256 + threadIdx.x]);
        if (threadIdx.x == 0) scal[w] = s / counts[w] + 1e-8f;
    }
}

__global__ __launch_bounds__(256) void k_quant(const float* __restrict__ W,
                                               const float* __restrict__ s_ptr,
                                               __hip_bfloat16* __restrict__ T) {
    int i = blockIdx.x * 256 + threadIdx.x;
    float s = *s_ptr;
    float q = rintf(W[i] / s);
    q = fmaxf(-1.0f, fminf(1.0f, q));
    T[i] = __float2bfloat16(q);
}

// ---------------- bitshift_norm ----------------
__global__ __launch_bounds__(256) void k_norm(const float* __restrict__ x,
                                              const float* __restrict__ gamma,
                                              const float* __restrict__ step,
                                              __hip_bfloat16* __restrict__ xn) {
    int row = blockIdx.x;
    const float* xr = x + (size_t)row * DM;
    float s = 0.f;
    for (int i = threadIdx.x; i < DM; i += 256) s += xr[i];
    float mean = block_reduce_sum(s) * (1.0f / DM);
    float v = 0.f;
    for (int i = threadIdx.x; i < DM; i += 256) { float d = xr[i] - mean; v += d * d; }
    float var = block_reduce_sum(v) * (1.0f / DM);
    float sc = pow2scale(var);
    float st = step[0];
    for (int i = threadIdx.x; i < DM; i += 256) {
        float val = ((xr[i] - mean) * sc) * gamma[i] * st;
        xn[(size_t)row * DM + i] = __float2bfloat16(val);
    }
}

// ---------------- MFMA GEMM (m97 structure): C = A[M,K] @ B[N,K]^T ----------------
// Unpadded LDS + global_load_lds width=16 staging, 2-barrier K-loop.
// MODE 0: xz epilogue  (col<DI -> xc f32 ; col>=DI -> bf16 squareplus(z))
// MODE 1: plain bf16 out
// MODE 2: dt -> sigmoid -> dyadic u16 decay
// MODE 3: f32 out + residual
template <int BM, int BN, int WR, int WC, int MODE>
__global__ __launch_bounds__(256) void k_gemm(
    const __hip_bfloat16* __restrict__ A, const __hip_bfloat16* __restrict__ Bw,
    int M, int N, int K, const float* __restrict__ s_ptr,
    float* __restrict__ o_f32, __hip_bfloat16* __restrict__ o_bf16,
    unsigned short* __restrict__ o_u16,
    const float* __restrict__ bias, const float* __restrict__ resid) {
    constexpr int BK = 32;
    constexpr int FM = BM / (WR * 16), FN = BN / (WC * 16);
    constexpr int RA = (BM * BK) / (256 * 8);  // async-16B rounds for A tile
    constexpr int RB = (BN * BK) / (256 * 8);
    __shared__ __align__(16) short lA[BM * BK];
    __shared__ __align__(16) short lB[BN * BK];
    const int tid = threadIdx.x;
    const int lane = tid & 63, wid = tid >> 6;
    const int wm = (wid / WC) * (BM / WR);
    const int wn = (wid % WC) * (BN / WC);
    const int r16 = lane & 15, quad = lane >> 4;
    const int m0 = blockIdx.y * BM, n0 = blockIdx.x * BN;

    floatx4 acc[FM][FN] = {};

    for (int k0 = 0; k0 < K; k0 += BK) {
        __syncthreads();
#pragma unroll
        for (int r = 0; r < RA; ++r) {
            int idx = r * 256 + tid;               // 16-byte chunk index
            int row = idx >> 2, kc = (idx & 3) << 3;
            async16(&A[(size_t)(m0 + row) * K + k0 + kc], &lA[idx * 8]);
        }
#pragma unroll
        for (int r = 0; r < RB; ++r) {
            int idx = r * 256 + tid;
            int row = idx >> 2, kc = (idx & 3) << 3;
            async16(&Bw[(size_t)(n0 + row) * K + k0 + kc], &lB[idx * 8]);
        }
        __syncthreads();  // vmcnt(0) drain + barrier
        short8 af[FM], bfv[FN];
#pragma unroll
        for (int i = 0; i < FM; ++i)
            af[i] = *reinterpret_cast<const short8*>(&lA[(wm + i * 16 + r16) * BK + quad * 8]);
#pragma unroll
        for (int j = 0; j < FN; ++j)
            bfv[j] = *reinterpret_cast<const short8*>(&lB[(wn + j * 16 + r16) * BK + quad * 8]);
#pragma unroll
        for (int i = 0; i < FM; ++i)
#pragma unroll
            for (int j = 0; j < FN; ++j)
                acc[i][j] = __builtin_amdgcn_mfma_f32_16x16x32_bf16(af[i], bfv[j], acc[i][j], 0, 0, 0);
    }

    const float s = *s_ptr;
#pragma unroll
    for (int i = 0; i < FM; ++i) {
#pragma unroll
        for (int j = 0; j < FN; ++j) {
#pragma unroll
            for (int r = 0; r < 4; ++r) {
                int gr = m0 + wm + i * 16 + quad * 4 + r;
                int gc = n0 + wn + j * 16 + r16;
                float v = acc[i][j][r] * s;
                if (MODE == 0) {
                    if (gc < DI) o_f32[(size_t)gr * DI + gc] = v;
                    else o_bf16[(size_t)gr * DI + (gc - DI)] = __float2bfloat16(squareplus_f(v));
                } else if (MODE == 1) {
                    o_bf16[(size_t)gr * N + gc] = __float2bfloat16(v);
                } else if (MODE == 2) {
                    float dt = v + bias[gc];
                    float dc = 0.5f + 0.5f * dt / (1.0f + fabsf(dt));
                    o_u16[(size_t)gr * N + gc] = (unsigned short)rintf(dc * 32768.0f);
                } else {
                    o_f32[(size_t)gr * N + gc] = v + resid[(size_t)gr * N + gc];
                }
            }
        }
    }
}

// ---------------- causal depthwise conv (k=4) + bias + squareplus ----------------
__global__ __launch_bounds__(256) void k_conv(const float* __restrict__ xc,
                                              const float* __restrict__ cw,
                                              const float* __restrict__ cb,
                                              __hip_bfloat16* __restrict__ xact) {
    int c = blockIdx.x * 256 + threadIdx.x;
    int t0 = blockIdx.y * CHUNK;
    int b = blockIdx.z;
    float w0 = cw[c * 4 + 0], w1 = cw[c * 4 + 1], w2 = cw[c * 4 + 2], w3 = cw[c * 4 + 3];
    float bias = cb[c];
    const float* base = xc + (size_t)b * L_ * DI + c;
    float x3 = (t0 - 3 >= 0) ? base[(size_t)(t0 - 3) * DI] : 0.f;
    float x2 = (t0 - 2 >= 0) ? base[(size_t)(t0 - 2) * DI] : 0.f;
    float x1 = (t0 - 1 >= 0) ? base[(size_t)(t0 - 1) * DI] : 0.f;
    for (int t = t0; t < t0 + CHUNK; ++t) {
        float xt = base[(size_t)t * DI];
        float y = x3 * w0 + x2 * w1 + x1 * w2 + xt * w3 + bias;
        xact[((size_t)(b * L_ + t)) * DI + c] = __float2bfloat16(squareplus_f(y));
        x3 = x2; x2 = x1; x1 = xt;
    }
}

// ---------------- 3-pass chunked linear scan ----------------
__global__ __launch_bounds__(256) void k_scan1(const unsigned short* __restrict__ dk,
                                               const __hip_bfloat16* __restrict__ u,
                                               float* __restrict__ cA, float* __restrict__ cB) {
    int c = blockIdx.x * 256 + threadIdx.x;
    int j = blockIdx.y, b = blockIdx.z;
    size_t base = ((size_t)b * L_ + (size_t)j * CHUNK) * DI + c;
    float Ac = 1.f, Bc = 0.f;
    for (int t = 0; t < CHUNK; ++t) {
        float a = dk[base + (size_t)t * DI] * (1.0f / 32768.0f);
        float uv = __bfloat162float(u[base + (size_t)t * DI]);
        Bc = a * Bc + (1.f - a) * uv;
        Ac *= a;
    }
    size_t o = ((size_t)(b * NCHUNK + j)) * DI + c;
    cA[o] = Ac;
    cB[o] = Bc;
}

__global__ __launch_bounds__(256) void k_scan2(const float* __restrict__ cA,
                                               const float* __restrict__ cB,
                                               float* __restrict__ pre) {
    int idx = blockIdx.x * 256 + threadIdx.x;  // b*DI + c
    int b = idx >> 11, c = idx & (DI - 1);
    float h = 0.f;
    for (int j = 0; j < NCHUNK; ++j) {
        size_t o = ((size_t)(b * NCHUNK + j)) * DI + c;
        pre[o] = h;
        h = cA[o] * h + cB[o];
    }
}

__global__ __launch_bounds__(256) void k_scan3(const unsigned short* __restrict__ dk,
                                               const __hip_bfloat16* __restrict__ u,
                                               const __hip_bfloat16* __restrict__ zsp,
                                               const float* __restrict__ pre,
                                               __hip_bfloat16* __restrict__ y) {
    int c = blockIdx.x * 256 + threadIdx.x;
    int j = blockIdx.y, b = blockIdx.z;
    size_t base = ((size_t)b * L_ + (size_t)j * CHUNK) * DI + c;
    float h = pre[((size_t)(b * NCHUNK + j)) * DI + c];
    for (int t = 0; t < CHUNK; ++t) {
        float a = dk[base + (size_t)t * DI] * (1.0f / 32768.0f);
        float uv = __bfloat162float(u[base + (size_t)t * DI]);
        h = a * h + (1.f - a) * uv;
        float yv = h * __bfloat162float(zsp[base + (size_t)t * DI]);
        y[base + (size_t)t * DI] = __float2bfloat16(yv);
    }
}

// ---------------- launch ----------------
extern "C" void kernel_launch(void* const* d_in, const int* in_sizes, int n_in,
                              void* d_out, int out_size, void* d_ws, size_t ws_size,
                              hipStream_t stream) {
    const float* x      = (const float*)d_in[0];
    const float* gamma  = (const float*)d_in[1];
    const float* step   = (const float*)d_in[2];
    const float* W_in   = (const float*)d_in[3];
    const float* conv_w = (const float*)d_in[4];
    const float* conv_b = (const float*)d_in[5];
    const float* W_x    = (const float*)d_in[6];
    const float* W_dt   = (const float*)d_in[7];
    const float* b_dt   = (const float*)d_in[8];
    const float* W_out  = (const float*)d_in[9];

    char* ws = (char*)d_ws;
    float*          scal = (float*)(ws + OFF_SCAL);
    float*          part = (float*)(ws + OFF_PART);
    __hip_bfloat16* xn   = (__hip_bfloat16*)(ws + OFF_XN);
    __hip_bfloat16* Tin  = (__hip_bfloat16*)(ws + OFF_TIN);
    __hip_bfloat16* Tx   = (__hip_bfloat16*)(ws + OFF_TX);
    __hip_bfloat16* Tdt  = (__hip_bfloat16*)(ws + OFF_TDT);
    __hip_bfloat16* Tout = (__hip_bfloat16*)(ws + OFF_TOUT);
    float*          xcf  = (float*)(ws + OFF_XC);
    __hip_bfloat16* zsp  = (__hip_bfloat16*)(ws + OFF_ZSP);
    __hip_bfloat16* xact = (__hip_bfloat16*)(ws + OFF_XACT);
    __hip_bfloat16* dbl  = (__hip_bfloat16*)(ws + OFF_DBL);
    unsigned short* dec  = (unsigned short*)(ws + OFF_DEC);
    float*          cA   = (float*)(ws + OFF_CA);
    float*          cB   = (float*)(ws + OFF_CB);
    float*          pre  = (float*)(ws + OFF_PRE);
    __hip_bfloat16* yb   = (__hip_bfloat16*)(ws + OFF_Y);
    float*          out  = (float*)d_out;

    // weight scales (deterministic two-stage reductions) + ternary quantization
    k_abs_partial<<<256, 256, 0, stream>>>(W_in, 2 * DI * DM, part + 0 * 256);
    k_abs_partial<<<256, 256, 0, stream>>>(W_x, 96 * DI, part + 1 * 256);
    k_abs_partial<<<256, 256, 0, stream>>>(W_dt, DI * DTR, part + 2 * 256);
    k_abs_partial<<<256, 256, 0, stream>>>(W_out, DM * DI, part + 3 * 256);
    k_finalize<<<1, 256, 0, stream>>>(part, scal);
    k_quant<<<(2 * DI * DM) / 256, 256, 0, stream>>>(W_in, scal + 0, Tin);
    k_quant<<<(DTR * DI) / 256, 256, 0, stream>>>(W_x, scal + 1, Tx);     // only first 64 rows used
    k_quant<<<(DI * DTR) / 256, 256, 0, stream>>>(W_dt, scal + 2, Tdt);
    k_quant<<<(DM * DI) / 256, 256, 0, stream>>>(W_out, scal + 3, Tout);

    // norm -> xn (bf16)
    k_norm<<<NR, 256, 0, stream>>>(x, gamma, step, xn);

    // GEMM1: xz = xn @ T_in^T * s ; split -> xc f32, sp(z) bf16
    k_gemm<128, 128, 2, 2, 0><<<dim3((2 * DI) / 128, NR / 128), 256, 0, stream>>>(
        xn, Tin, NR, 2 * DI, DM, scal + 0, xcf, zsp, nullptr, nullptr, nullptr);

    // conv + bias + squareplus -> xact (bf16)
    k_conv<<<dim3(DI / 256, L_ / CHUNK, B_), 256, 0, stream>>>(xcf, conv_w, conv_b, xact);

    // GEMM2: dbl = xact @ T_x[:64]^T * s  -> bf16 [NR,64]  (BM=64 for 128-block parallelism)
    k_gemm<64, 64, 2, 2, 1><<<dim3(1, NR / 64), 256, 0, stream>>>(
        xact, Tx, NR, DTR, DI, scal + 1, nullptr, dbl, nullptr, nullptr, nullptr);

    // GEMM3: dt = dbl @ T_dt^T * s + b_dt -> sigmoid -> dyadic u16 decay
    k_gemm<128, 128, 2, 2, 2><<<dim3(DI / 128, NR / 128), 256, 0, stream>>>(
        dbl, Tdt, NR, DI, DTR, scal + 2, nullptr, nullptr, dec, b_dt, nullptr);

    // scan (3 passes), pass3 fuses y = h * sp(z) -> bf16
    k_scan1<<<dim3(DI / 256, NCHUNK, B_), 256, 0, stream>>>(dec, xact, cA, cB);
    k_scan2<<<(B_ * DI) / 256, 256, 0, stream>>>(cA, cB, pre);
    k_scan3<<<dim3(DI / 256, NCHUNK, B_), 256, 0, stream>>>(dec, xact, zsp, pre, yb);

    // GEMM4: out = y @ T_out^T * s + residual
    k_gemm<128, 128, 2, 2, 3><<<dim3(DM / 128, NR / 128), 256, 0, stream>>>(
        yb, Tout, NR, DM, DI, scal + 3, out, nullptr, nullptr, nullptr, x);

    (void)in_sizes; (void)n_in; (void)out_size; (void)ws_size;
}

// Round 3
// 452.340 us; speedup vs baseline: 1.2911x; 1.0741x over previous
//
#include <hip/hip_runtime.h>
#include <hip/hip_bf16.h>

#define B_ 4
#define L_ 2048
#define DM 1024
#define DI 2048
#define NR (B_ * L_)   // 8192 rows
#define DTR 64
#define NCHUNK 16
#define CHUNK 128

typedef __attribute__((ext_vector_type(8))) short short8;
typedef __attribute__((ext_vector_type(4))) float floatx4;

// ---------------- workspace layout (bytes) ----------------
static constexpr size_t OFF_SCAL = 0;                                    // 4 f32 scales
static constexpr size_t OFF_PART = 256;                                  // 4*256 f32 partials
static constexpr size_t OFF_XN   = 4608;                                 // xn bf16 [NR,DM]
static constexpr size_t OFF_TIN  = OFF_XN   + (size_t)NR * DM * 2;       // T_in bf16 [4096,1024]
static constexpr size_t OFF_TX   = OFF_TIN  + (size_t)2 * DI * DM * 2;   // T_x bf16 [64,2048]
static constexpr size_t OFF_TDT  = OFF_TX   + (size_t)DTR * DI * 2;      // T_dt bf16 [2048,64]
static constexpr size_t OFF_TOUT = OFF_TDT  + (size_t)DI * DTR * 2;      // T_out bf16 [1024,2048]
static constexpr size_t OFF_XC   = OFF_TOUT + (size_t)DM * DI * 2;       // xc bf16 [NR,DI]
static constexpr size_t OFF_ZSP  = OFF_XC   + (size_t)NR * DI * 4;       // z raw bf16 [NR,DI]
static constexpr size_t OFF_XACT = OFF_ZSP  + (size_t)NR * DI * 2;       // sp(conv) bf16 [NR,DI]
static constexpr size_t OFF_DBL  = OFF_XACT + (size_t)NR * DI * 2;       // dbl bf16 [NR,64]
static constexpr size_t OFF_DEC  = OFF_DBL  + (size_t)NR * DTR * 2;      // decay u16 [NR,DI]
static constexpr size_t OFF_CA   = OFF_DEC  + (size_t)NR * DI * 2;       // chunk A f32 [B,16,DI]
static constexpr size_t OFF_CB   = OFF_CA   + (size_t)B_ * NCHUNK * DI * 4;
static constexpr size_t OFF_PRE  = OFF_CB   + (size_t)B_ * NCHUNK * DI * 4;
static constexpr size_t OFF_Y    = OFF_PRE  + (size_t)B_ * NCHUNK * DI * 4; // y bf16 [NR,DI]

// ---------------- async global->LDS (16B per lane, wave-uniform base rule) ----------------
__device__ __forceinline__ void async16(const void* g, void* l) {
    __builtin_amdgcn_global_load_lds(
        (const __attribute__((address_space(1))) unsigned int*)g,
        (__attribute__((address_space(3))) unsigned int*)l, 16, 0, 0);
}

// ---------------- scalar math (bit-faithful to reference) ----------------
__device__ __forceinline__ float pow2scale(float var) {
    float v = var + 1e-9f;
    float s = 1.0f;
    if (v >= 4.0f)     s = 0.5f;
    if (v >= 16.0f)    s = 0.25f;
    if (v >= 64.0f)    s = 0.125f;
    if (v >= 256.0f)   s = 0.0625f;
    if (v >= 1024.0f)  s = 0.03125f;
    if (v >= 4096.0f)  s = 0.015625f;
    if (v >= 16384.0f) s = 0.0078125f;
    if (v >= 65536.0f) s = 0.00390625f;
    if (v < 1.0f)    s = 1.0f;
    if (v < 0.25f)   s = 2.0f;
    if (v < 0.0625f) s = 4.0f;
    return s;
}

__device__ __forceinline__ float squareplus_f(float x) {
    float y = fminf(fmaxf(x * x + 4.0f, 1e-6f), 1e6f);
    float r = (y > 16.0f) ? 0.125f : 0.5f;
    if (y > 64.0f)  r = 0.0625f;
    if (y > 256.0f) r = 0.03125f;
    if (y < 4.0f)   r = 1.0f;
    if (y < 1.0f)   r = 2.0f;
    if (y < 0.25f)  r = 4.0f;
#pragma unroll
    for (int i = 0; i < 3; ++i) {
        r = r * (1.5f - 0.5f * y * r * r);
        r = fminf(fmaxf(r, 1e-6f), 1e3f);
    }
    float s = fminf(fmaxf(y * r, 0.0f), 1e3f);
    return 0.5f * (x + s);
}

__device__ __forceinline__ float block_reduce_sum(float v) {
    __shared__ float sm[4];
#pragma unroll
    for (int o = 32; o > 0; o >>= 1) v += __shfl_down(v, o, 64);
    int w = threadIdx.x >> 6;
    __syncthreads();
    if ((threadIdx.x & 63) == 0) sm[w] = v;
    __syncthreads();
    return (sm[0] + sm[1]) + (sm[2] + sm[3]);
}

// ---------------- weight-scale reduction + ternary quantization ----------------
__global__ __launch_bounds__(256) void k_abs_partial(const float* __restrict__ W, int n,
                                                     float* __restrict__ part) {
    float s = 0.f;
    for (int i = blockIdx.x * 256 + threadIdx.x; i < n; i += 256 * gridDim.x)
        s += fabsf(W[i]);
    float t = block_reduce_sum(s);
    if (threadIdx.x == 0) part[blockIdx.x] = t;
}

__global__ __launch_bounds__(256) void k_finalize(const float* __restrict__ part,
                                                  float* __restrict__ scal) {
    const float counts[4] = {(float)(2 * DI * DM), (float)(96 * DI),
                             (float)(DI * DTR), (float)(DM * DI)};
    for (int w = 0; w < 4; ++w) {
        float s = block_reduce_sum(part[w * 256 + threadIdx.x]);
        if (threadIdx.x == 0) scal[w] = s / counts[w] + 1e-8f;
    }
}

__global__ __launch_bounds__(256) void k_quant(const float* __restrict__ W,
                                               const float* __restrict__ s_ptr,
                                               __hip_bfloat16* __restrict__ T) {
    int i = blockIdx.x * 256 + threadIdx.x;
    float s = *s_ptr;
    float q = rintf(W[i] / s);
    q = fmaxf(-1.0f, fminf(1.0f, q));
    T[i] = __float2bfloat16(q);
}

// ---------------- bitshift_norm ----------------
__global__ __launch_bounds__(256) void k_norm(const float* __restrict__ x,
                                              const float* __restrict__ gamma,
                                              const float* __restrict__ step,
                                              __hip_bfloat16* __restrict__ xn) {
    int row = blockIdx.x;
    const float* xr = x + (size_t)row * DM;
    float s = 0.f;
    for (int i = threadIdx.x; i < DM; i += 256) s += xr[i];
    float mean = block_reduce_sum(s) * (1.0f / DM);
    float v = 0.f;
    for (int i = threadIdx.x; i < DM; i += 256) { float d = xr[i] - mean; v += d * d; }
    float var = block_reduce_sum(v) * (1.0f / DM);
    float sc = pow2scale(var);
    float st = step[0];
    for (int i = threadIdx.x; i < DM; i += 256) {
        float val = ((xr[i] - mean) * sc) * gamma[i] * st;
        xn[(size_t)row * DM + i] = __float2bfloat16(val);
    }
}

// ---------------- MFMA GEMM, double-buffered pipeline: C = A[M,K] @ B[N,K]^T ----------------
// Raw s_barrier + fine vmcnt(KEEP): prefetch of tile t+1 stays in flight across compute of t.
// MODE 0: xz epilogue  (col<DI -> xc bf16 ; col>=DI -> raw z bf16)
// MODE 1: plain bf16 out
// MODE 2: dt -> sigmoid -> dyadic u16 decay
// MODE 3: f32 out + residual
template <int BM, int BN, int WR, int WC, int MODE>
__global__ __launch_bounds__(256) void k_gemm(
    const __hip_bfloat16* __restrict__ A, const __hip_bfloat16* __restrict__ Bw,
    int M, int N, int K, const float* __restrict__ s_ptr,
    float* __restrict__ o_f32, __hip_bfloat16* __restrict__ o_bf16,
    unsigned short* __restrict__ o_u16,
    const float* __restrict__ bias, const float* __restrict__ resid) {
    constexpr int BK = 32;
    constexpr int FM = BM / (WR * 16), FN = BN / (WC * 16);
    constexpr int RA = (BM * BK) / (256 * 8);  // async-16B rounds for A tile
    constexpr int RB = (BN * BK) / (256 * 8);
    constexpr int KEEP = RA + RB;              // loads in flight per thread per tile
    __shared__ __align__(16) short lA[2][BM * BK];
    __shared__ __align__(16) short lB[2][BN * BK];
    const int tid = threadIdx.x;
    const int lane = tid & 63, wid = tid >> 6;
    const int wm = (wid / WC) * (BM / WR);
    const int wn = (wid % WC) * (BN / WC);
    const int r16 = lane & 15, quad = lane >> 4;

    // XCD-aware swizzle: give each XCD a contiguous strip of N-tiles (B stays L2-hot)
    int nx = gridDim.x;
    int bx = blockIdx.x, by = blockIdx.y;
    if ((nx & 7) == 0) {
        int bid = by * nx + bx;
        int xcd = bid & 7, idx = bid >> 3;
        int npx = nx >> 3;
        bx = xcd * npx + (idx % npx);
        by = idx / npx;
    }
    const int m0 = by * BM, n0 = bx * BN;

    floatx4 acc[FM][FN] = {};
    const int NT = K / BK;

    // prefetch tile 0 -> buffer 0
#pragma unroll
    for (int r = 0; r < RA; ++r) {
        int idx = r * 256 + tid;
        int row = idx >> 2, kc = (idx & 3) << 3;
        async16(&A[(size_t)(m0 + row) * K + kc], &lA[0][idx * 8]);
    }
#pragma unroll
    for (int r = 0; r < RB; ++r) {
        int idx = r * 256 + tid;
        int row = idx >> 2, kc = (idx & 3) << 3;
        async16(&Bw[(size_t)(n0 + row) * K + kc], &lB[0][idx * 8]);
    }

    for (int t = 0; t < NT; ++t) {
        // barrier A: everyone done reading buf[(t+1)&1] (tile t-1) -> safe to overwrite
        if (t > 0) __builtin_amdgcn_s_barrier();
        if (t + 1 < NT) {
            const int k1 = (t + 1) * BK;
            const int nb = (t + 1) & 1;
#pragma unroll
            for (int r = 0; r < RA; ++r) {
                int idx = r * 256 + tid;
                int row = idx >> 2, kc = (idx & 3) << 3;
                async16(&A[(size_t)(m0 + row) * K + k1 + kc], &lA[nb][idx * 8]);
            }
#pragma unroll
            for (int r = 0; r < RB; ++r) {
                int idx = r * 256 + tid;
                int row = idx >> 2, kc = (idx & 3) << 3;
                async16(&Bw[(size_t)(n0 + row) * K + k1 + kc], &lB[nb][idx * 8]);
            }
            __builtin_amdgcn_s_waitcnt(0x0F70 | KEEP);  // tile t done; prefetch in flight
        } else {
            __builtin_amdgcn_s_waitcnt(0x0F70);         // vmcnt(0), no lgkm/exp wait
        }
        __builtin_amdgcn_s_barrier();                    // barrier B: tile t visible to all

        const int cb = t & 1;
        short8 af[FM], bfv[FN];
#pragma unroll
        for (int i = 0; i < FM; ++i)
            af[i] = *reinterpret_cast<const short8*>(&lA[cb][(wm + i * 16 + r16) * BK + quad * 8]);
#pragma unroll
        for (int j = 0; j < FN; ++j)
            bfv[j] = *reinterpret_cast<const short8*>(&lB[cb][(wn + j * 16 + r16) * BK + quad * 8]);
#pragma unroll
        for (int i = 0; i < FM; ++i)
#pragma unroll
            for (int j = 0; j < FN; ++j)
                acc[i][j] = __builtin_amdgcn_mfma_f32_16x16x32_bf16(af[i], bfv[j], acc[i][j], 0, 0, 0);
    }

    const float s = *s_ptr;
#pragma unroll
    for (int i = 0; i < FM; ++i) {
#pragma unroll
        for (int j = 0; j < FN; ++j) {
#pragma unroll
            for (int r = 0; r < 4; ++r) {
                int gr = m0 + wm + i * 16 + quad * 4 + r;
                int gc = n0 + wn + j * 16 + r16;
                float v = acc[i][j][r] * s;
                if (MODE == 0) {
                    if (gc < DI) o_bf16[(size_t)gr * DI + gc] = __float2bfloat16(v);
                    else o_f32 ? (void)0 : (void)0, ((__hip_bfloat16*)o_f32)[(size_t)gr * DI + (gc - DI)] = __float2bfloat16(v);
                } else if (MODE == 1) {
                    o_bf16[(size_t)gr * N + gc] = __float2bfloat16(v);
                } else if (MODE == 2) {
                    float dt = v + bias[gc];
                    float dc = 0.5f + 0.5f * dt / (1.0f + fabsf(dt));
                    o_u16[(size_t)gr * N + gc] = (unsigned short)rintf(dc * 32768.0f);
                } else {
                    o_f32[(size_t)gr * N + gc] = v + resid[(size_t)gr * N + gc];
                }
            }
        }
    }
}

// ---------------- causal depthwise conv (k=4, bf16 in) + bias + squareplus ----------------
__global__ __launch_bounds__(256) void k_conv(const __hip_bfloat16* __restrict__ xc,
                                              const float* __restrict__ cw,
                                              const float* __restrict__ cb,
                                              __hip_bfloat16* __restrict__ xact) {
    int c = blockIdx.x * 256 + threadIdx.x;
    int t0 = blockIdx.y * CHUNK;
    int b = blockIdx.z;
    float w0 = cw[c * 4 + 0], w1 = cw[c * 4 + 1], w2 = cw[c * 4 + 2], w3 = cw[c * 4 + 3];
    float bias = cb[c];
    const __hip_bfloat16* base = xc + (size_t)b * L_ * DI + c;
    float x3 = (t0 - 3 >= 0) ? __bfloat162float(base[(size_t)(t0 - 3) * DI]) : 0.f;
    float x2 = (t0 - 2 >= 0) ? __bfloat162float(base[(size_t)(t0 - 2) * DI]) : 0.f;
    float x1 = (t0 - 1 >= 0) ? __bfloat162float(base[(size_t)(t0 - 1) * DI]) : 0.f;
    for (int t = t0; t < t0 + CHUNK; ++t) {
        float xt = __bfloat162float(base[(size_t)t * DI]);
        float y = x3 * w0 + x2 * w1 + x1 * w2 + xt * w3 + bias;
        xact[((size_t)(b * L_ + t)) * DI + c] = __float2bfloat16(squareplus_f(y));
        x3 = x2; x2 = x1; x1 = xt;
    }
}

// ---------------- 3-pass chunked linear scan ----------------
__global__ __launch_bounds__(256) void k_scan1(const unsigned short* __restrict__ dk,
                                               const __hip_bfloat16* __restrict__ u,
                                               float* __restrict__ cA, float* __restrict__ cB) {
    int c = blockIdx.x * 256 + threadIdx.x;
    int j = blockIdx.y, b = blockIdx.z;
    size_t base = ((size_t)b * L_ + (size_t)j * CHUNK) * DI + c;
    float Ac = 1.f, Bc = 0.f;
    for (int t = 0; t < CHUNK; ++t) {
        float a = dk[base + (size_t)t * DI] * (1.0f / 32768.0f);
        float uv = __bfloat162float(u[base + (size_t)t * DI]);
        Bc = a * Bc + (1.f - a) * uv;
        Ac *= a;
    }
    size_t o = ((size_t)(b * NCHUNK + j)) * DI + c;
    cA[o] = Ac;
    cB[o] = Bc;
}

__global__ __launch_bounds__(256) void k_scan2(const float* __restrict__ cA,
                                               const float* __restrict__ cB,
                                               float* __restrict__ pre) {
    int idx = blockIdx.x * 256 + threadIdx.x;  // b*DI + c
    int b = idx >> 11, c = idx & (DI - 1);
    float h = 0.f;
    for (int j = 0; j < NCHUNK; ++j) {
        size_t o = ((size_t)(b * NCHUNK + j)) * DI + c;
        pre[o] = h;
        h = cA[o] * h + cB[o];
    }
}

__global__ __launch_bounds__(256) void k_scan3(const unsigned short* __restrict__ dk,
                                               const __hip_bfloat16* __restrict__ u,
                                               const __hip_bfloat16* __restrict__ zraw,
                                               const float* __restrict__ pre,
                                               __hip_bfloat16* __restrict__ y) {
    int c = blockIdx.x * 256 + threadIdx.x;
    int j = blockIdx.y, b = blockIdx.z;
    size_t base = ((size_t)b * L_ + (size_t)j * CHUNK) * DI + c;
    float h = pre[((size_t)(b * NCHUNK + j)) * DI + c];
    for (int t = 0; t < CHUNK; ++t) {
        float a = dk[base + (size_t)t * DI] * (1.0f / 32768.0f);
        float uv = __bfloat162float(u[base + (size_t)t * DI]);
        h = a * h + (1.f - a) * uv;
        float zv = squareplus_f(__bfloat162float(zraw[base + (size_t)t * DI]));
        y[base + (size_t)t * DI] = __float2bfloat16(h * zv);
    }
}

// ---------------- launch ----------------
extern "C" void kernel_launch(void* const* d_in, const int* in_sizes, int n_in,
                              void* d_out, int out_size, void* d_ws, size_t ws_size,
                              hipStream_t stream) {
    const float* x      = (const float*)d_in[0];
    const float* gamma  = (const float*)d_in[1];
    const float* step   = (const float*)d_in[2];
    const float* W_in   = (const float*)d_in[3];
    const float* conv_w = (const float*)d_in[4];
    const float* conv_b = (const float*)d_in[5];
    const float* W_x    = (const float*)d_in[6];
    const float* W_dt   = (const float*)d_in[7];
    const float* b_dt   = (const float*)d_in[8];
    const float* W_out  = (const float*)d_in[9];

    char* ws = (char*)d_ws;
    float*          scal = (float*)(ws + OFF_SCAL);
    float*          part = (float*)(ws + OFF_PART);
    __hip_bfloat16* xn   = (__hip_bfloat16*)(ws + OFF_XN);
    __hip_bfloat16* Tin  = (__hip_bfloat16*)(ws + OFF_TIN);
    __hip_bfloat16* Tx   = (__hip_bfloat16*)(ws + OFF_TX);
    __hip_bfloat16* Tdt  = (__hip_bfloat16*)(ws + OFF_TDT);
    __hip_bfloat16* Tout = (__hip_bfloat16*)(ws + OFF_TOUT);
    __hip_bfloat16* xcb  = (__hip_bfloat16*)(ws + OFF_XC);
    __hip_bfloat16* zraw = (__hip_bfloat16*)(ws + OFF_ZSP);
    __hip_bfloat16* xact = (__hip_bfloat16*)(ws + OFF_XACT);
    __hip_bfloat16* dbl  = (__hip_bfloat16*)(ws + OFF_DBL);
    unsigned short* dec  = (unsigned short*)(ws + OFF_DEC);
    float*          cA   = (float*)(ws + OFF_CA);
    float*          cB   = (float*)(ws + OFF_CB);
    float*          pre  = (float*)(ws + OFF_PRE);
    __hip_bfloat16* yb   = (__hip_bfloat16*)(ws + OFF_Y);
    float*          out  = (float*)d_out;

    // weight scales (deterministic two-stage reductions) + ternary quantization
    k_abs_partial<<<256, 256, 0, stream>>>(W_in, 2 * DI * DM, part + 0 * 256);
    k_abs_partial<<<256, 256, 0, stream>>>(W_x, 96 * DI, part + 1 * 256);
    k_abs_partial<<<256, 256, 0, stream>>>(W_dt, DI * DTR, part + 2 * 256);
    k_abs_partial<<<256, 256, 0, stream>>>(W_out, DM * DI, part + 3 * 256);
    k_finalize<<<1, 256, 0, stream>>>(part, scal);
    k_quant<<<(2 * DI * DM) / 256, 256, 0, stream>>>(W_in, scal + 0, Tin);
    k_quant<<<(DTR * DI) / 256, 256, 0, stream>>>(W_x, scal + 1, Tx);     // only first 64 rows used
    k_quant<<<(DI * DTR) / 256, 256, 0, stream>>>(W_dt, scal + 2, Tdt);
    k_quant<<<(DM * DI) / 256, 256, 0, stream>>>(W_out, scal + 3, Tout);

    // norm -> xn (bf16)
    k_norm<<<NR, 256, 0, stream>>>(x, gamma, step, xn);

    // GEMM1: xz = xn @ T_in^T * s ; split -> xc bf16, z raw bf16
    // (MODE 0 uses o_bf16 = xc buffer, o_f32 slot carries the z buffer pointer)
    k_gemm<128, 128, 2, 2, 0><<<dim3((2 * DI) / 128, NR / 128), 256, 0, stream>>>(
        xn, Tin, NR, 2 * DI, DM, scal + 0, (float*)zraw, xcb, nullptr, nullptr, nullptr);

    // conv + bias + squareplus -> xact (bf16)
    k_conv<<<dim3(DI / 256, L_ / CHUNK, B_), 256, 0, stream>>>(xcb, conv_w, conv_b, xact);

    // GEMM2: dbl = xact @ T_x[:64]^T * s  -> bf16 [NR,64]
    k_gemm<64, 64, 2, 2, 1><<<dim3(1, NR / 64), 256, 0, stream>>>(
        xact, Tx, NR, DTR, DI, scal + 1, nullptr, dbl, nullptr, nullptr, nullptr);

    // GEMM3: dt = dbl @ T_dt^T * s + b_dt -> sigmoid -> dyadic u16 decay
    k_gemm<128, 128, 2, 2, 2><<<dim3(DI / 128, NR / 128), 256, 0, stream>>>(
        dbl, Tdt, NR, DI, DTR, scal + 2, nullptr, nullptr, dec, b_dt, nullptr);

    // scan (3 passes), pass3 fuses y = h * squareplus(z) -> bf16
    k_scan1<<<dim3(DI / 256, NCHUNK, B_), 256, 0, stream>>>(dec, xact, cA, cB);
    k_scan2<<<(B_ * DI) / 256, 256, 0, stream>>>(cA, cB, pre);
    k_scan3<<<dim3(DI / 256, NCHUNK, B_), 256, 0, stream>>>(dec, xact, zraw, pre, yb);

    // GEMM4: out = y @ T_out^T * s + residual
    k_gemm<128, 128, 2, 2, 3><<<dim3(DM / 128, NR / 128), 256, 0, stream>>>(
        yb, Tout, NR, DM, DI, scal + 3, out, nullptr, nullptr, nullptr, x);

    (void)in_sizes; (void)n_in; (void)out_size; (void)ws_size;
}

// Round 4
// 416.785 us; speedup vs baseline: 1.4012x; 1.0853x over previous
//
#include <hip/hip_runtime.h>
#include <hip/hip_bf16.h>

#define B_ 4
#define L_ 2048
#define DM 1024
#define DI 2048
#define NR (B_ * L_)   // 8192 rows
#define DTR 64
#define NCHUNK 16
#define CHUNK 128
#define KSLICE 8       // split-K slices for GEMM2

typedef __attribute__((ext_vector_type(8))) short short8;
typedef __attribute__((ext_vector_type(4))) float floatx4;

// ---------------- workspace layout (bytes) ----------------
static constexpr size_t OFF_SCAL = 0;                                    // 4 f32 scales
static constexpr size_t OFF_PART = 256;                                  // 4*256 f32 partials
static constexpr size_t OFF_XN   = 4608;                                 // xn bf16 [NR,DM]
static constexpr size_t OFF_TIN  = OFF_XN   + (size_t)NR * DM * 2;       // T_in bf16 [4096,1024]
static constexpr size_t OFF_TX   = OFF_TIN  + (size_t)2 * DI * DM * 2;   // T_x bf16 [64,2048]
static constexpr size_t OFF_TDT  = OFF_TX   + (size_t)DTR * DI * 2;      // T_dt bf16 [2048,64]
static constexpr size_t OFF_TOUT = OFF_TDT  + (size_t)DI * DTR * 2;      // T_out bf16 [1024,2048]
static constexpr size_t OFF_XC   = OFF_TOUT + (size_t)DM * DI * 2;       // xc bf16 [NR,DI]
static constexpr size_t OFF_P2   = OFF_XC   + (size_t)NR * DI * 2;       // GEMM2 f32 partials [8,NR,64] (xc-region slack; xc dead after conv)
static constexpr size_t OFF_ZSP  = OFF_XC   + (size_t)NR * DI * 4;       // z raw bf16 [NR,DI]
static constexpr size_t OFF_XACT = OFF_ZSP  + (size_t)NR * DI * 2;       // sp(conv) bf16 [NR,DI]
static constexpr size_t OFF_DBL  = OFF_XACT + (size_t)NR * DI * 2;       // dbl bf16 [NR,64]
static constexpr size_t OFF_DEC  = OFF_DBL  + (size_t)NR * DTR * 2;      // decay u16 [NR,DI]
static constexpr size_t OFF_CA   = OFF_DEC  + (size_t)NR * DI * 2;       // chunk A f32 [B,16,DI]
static constexpr size_t OFF_CB   = OFF_CA   + (size_t)B_ * NCHUNK * DI * 4;
static constexpr size_t OFF_Y    = OFF_CB   + (size_t)B_ * NCHUNK * DI * 4; // y bf16 [NR,DI]

// ---------------- async global->LDS (16B per lane, wave-uniform base rule) ----------------
__device__ __forceinline__ void async16(const void* g, void* l) {
    __builtin_amdgcn_global_load_lds(
        (const __attribute__((address_space(1))) unsigned int*)g,
        (__attribute__((address_space(3))) unsigned int*)l, 16, 0, 0);
}

// ---------------- scalar math (bit-faithful to reference) ----------------
__device__ __forceinline__ float pow2scale(float var) {
    float v = var + 1e-9f;
    float s = 1.0f;
    if (v >= 4.0f)     s = 0.5f;
    if (v >= 16.0f)    s = 0.25f;
    if (v >= 64.0f)    s = 0.125f;
    if (v >= 256.0f)   s = 0.0625f;
    if (v >= 1024.0f)  s = 0.03125f;
    if (v >= 4096.0f)  s = 0.015625f;
    if (v >= 16384.0f) s = 0.0078125f;
    if (v >= 65536.0f) s = 0.00390625f;
    if (v < 1.0f)    s = 1.0f;
    if (v < 0.25f)   s = 2.0f;
    if (v < 0.0625f) s = 4.0f;
    return s;
}

__device__ __forceinline__ float squareplus_f(float x) {
    float y = fminf(fmaxf(x * x + 4.0f, 1e-6f), 1e6f);
    float r = (y > 16.0f) ? 0.125f : 0.5f;
    if (y > 64.0f)  r = 0.0625f;
    if (y > 256.0f) r = 0.03125f;
    if (y < 4.0f)   r = 1.0f;
    if (y < 1.0f)   r = 2.0f;
    if (y < 0.25f)  r = 4.0f;
#pragma unroll
    for (int i = 0; i < 3; ++i) {
        r = r * (1.5f - 0.5f * y * r * r);
        r = fminf(fmaxf(r, 1e-6f), 1e3f);
    }
    float s = fminf(fmaxf(y * r, 0.0f), 1e3f);
    return 0.5f * (x + s);
}

__device__ __forceinline__ float block_reduce_sum(float v) {
    __shared__ float sm[4];
#pragma unroll
    for (int o = 32; o > 0; o >>= 1) v += __shfl_down(v, o, 64);
    int w = threadIdx.x >> 6;
    __syncthreads();
    if ((threadIdx.x & 63) == 0) sm[w] = v;
    __syncthreads();
    return (sm[0] + sm[1]) + (sm[2] + sm[3]);
}

// ---------------- fused weight-scale partials (all 4 weights, one launch) ----------------
__global__ __launch_bounds__(256) void k_abs_all(const float* __restrict__ W0,
                                                 const float* __restrict__ W1,
                                                 const float* __restrict__ W2,
                                                 const float* __restrict__ W3,
                                                 float* __restrict__ part) {
    const int w = blockIdx.y;
    const float* W = (w == 0) ? W0 : (w == 1) ? W1 : (w == 2) ? W2 : W3;
    const int n = (w == 0) ? 2 * DI * DM : (w == 1) ? 96 * DI : (w == 2) ? DI * DTR : DM * DI;
    float s = 0.f;
    for (int i = blockIdx.x * 256 + threadIdx.x; i < n; i += 256 * 256)
        s += fabsf(W[i]);
    float t = block_reduce_sum(s);
    if (threadIdx.x == 0) part[w * 256 + blockIdx.x] = t;
}

__global__ __launch_bounds__(256) void k_finalize(const float* __restrict__ part,
                                                  float* __restrict__ scal) {
    const float counts[4] = {(float)(2 * DI * DM), (float)(96 * DI),
                             (float)(DI * DTR), (float)(DM * DI)};
    for (int w = 0; w < 4; ++w) {
        float s = block_reduce_sum(part[w * 256 + threadIdx.x]);
        if (threadIdx.x == 0) scal[w] = s / counts[w] + 1e-8f;
    }
}

// ---------------- fused ternary quantization (all 4 weights, one launch) ----------------
// block segments: W_in 16384 | W_x(first 64 rows) 512 | W_dt 512 | W_out 8192  = 25600 blocks
__global__ __launch_bounds__(256) void k_quant_all(
    const float* __restrict__ W0, const float* __restrict__ W1,
    const float* __restrict__ W2, const float* __restrict__ W3,
    const float* __restrict__ scal,
    __hip_bfloat16* __restrict__ T0, __hip_bfloat16* __restrict__ T1,
    __hip_bfloat16* __restrict__ T2, __hip_bfloat16* __restrict__ T3) {
    int b = blockIdx.x;
    const float* W; const float* sp; __hip_bfloat16* T; int off;
    if (b < 16384)      { W = W0; sp = scal + 0; T = T0; off = b; }
    else if (b < 16896) { W = W1; sp = scal + 1; T = T1; off = b - 16384; }
    else if (b < 17408) { W = W2; sp = scal + 2; T = T2; off = b - 16896; }
    else                { W = W3; sp = scal + 3; T = T3; off = b - 17408; }
    int i = off * 256 + threadIdx.x;
    float s = *sp;
    float q = rintf(W[i] / s);
    q = fmaxf(-1.0f, fminf(1.0f, q));
    T[i] = __float2bfloat16(q);
}

// ---------------- bitshift_norm ----------------
__global__ __launch_bounds__(256) void k_norm(const float* __restrict__ x,
                                              const float* __restrict__ gamma,
                                              const float* __restrict__ step,
                                              __hip_bfloat16* __restrict__ xn) {
    int row = blockIdx.x;
    const float* xr = x + (size_t)row * DM;
    float s = 0.f;
    for (int i = threadIdx.x; i < DM; i += 256) s += xr[i];
    float mean = block_reduce_sum(s) * (1.0f / DM);
    float v = 0.f;
    for (int i = threadIdx.x; i < DM; i += 256) { float d = xr[i] - mean; v += d * d; }
    float var = block_reduce_sum(v) * (1.0f / DM);
    float sc = pow2scale(var);
    float st = step[0];
    for (int i = threadIdx.x; i < DM; i += 256) {
        float val = ((xr[i] - mean) * sc) * gamma[i] * st;
        xn[(size_t)row * DM + i] = __float2bfloat16(val);
    }
}

// ---------------- MFMA GEMM, depth-2 pipeline (3 LDS buffers): C = A[M,K] @ B[N,K]^T ----------------
// MODE 0: xz epilogue  (col<DI -> xc bf16 via o_bf16 ; col>=DI -> raw z bf16 via o_bf16b)
// MODE 1: plain bf16 out
// MODE 2: dt -> sigmoid -> dyadic u16 decay
// MODE 3: f32 out + residual
// MODE 4: f32 partial (split-K over blockIdx.z, no scale)
template <int BM, int BN, int WR, int WC, int MODE>
__global__ __launch_bounds__(256) void k_gemm(
    const __hip_bfloat16* __restrict__ A, const __hip_bfloat16* __restrict__ Bw,
    int M, int N, int K, int lda, int ldb, const float* __restrict__ s_ptr,
    float* __restrict__ o_f32, __hip_bfloat16* __restrict__ o_bf16,
    __hip_bfloat16* __restrict__ o_bf16b, unsigned short* __restrict__ o_u16,
    const float* __restrict__ bias, const float* __restrict__ resid) {
    constexpr int BK = 32;
    constexpr int FM = BM / (WR * 16), FN = BN / (WC * 16);
    constexpr int RA = (BM * BK) / (256 * 8);  // async-16B rounds for A tile
    constexpr int RB = (BN * BK) / (256 * 8);
    constexpr int KEEP = RA + RB;              // loads in flight per thread per tile
    __shared__ __align__(16) short lA[3][BM * BK];
    __shared__ __align__(16) short lB[3][BN * BK];
    const int tid = threadIdx.x;
    const int lane = tid & 63, wid = tid >> 6;
    const int wm = (wid / WC) * (BM / WR);
    const int wn = (wid % WC) * (BN / WC);
    const int r16 = lane & 15, quad = lane >> 4;

    // split-K slice offset
    if (MODE == 4) {
        A  += (size_t)blockIdx.z * K;
        Bw += (size_t)blockIdx.z * K;
        o_f32 += (size_t)blockIdx.z * M * N;
    }

    // XCD-aware swizzle: contiguous strip of N-tiles per XCD
    int nx = gridDim.x;
    int bx = blockIdx.x, by = blockIdx.y;
    if ((nx & 7) == 0 && nx >= 8) {
        int bid = by * nx + bx;
        int xcd = bid & 7, idx = bid >> 3;
        int npx = nx >> 3;
        bx = xcd * npx + (idx % npx);
        by = idx / npx;
    }
    const int m0 = by * BM, n0 = bx * BN;

    floatx4 acc[FM][FN] = {};
    const int NT = K / BK;

    // prologue: prefetch tiles 0 and 1
#pragma unroll
    for (int r = 0; r < RA; ++r) {
        int idx = r * 256 + tid;
        int row = idx >> 2, kc = (idx & 3) << 3;
        async16(&A[(size_t)(m0 + row) * lda + kc], &lA[0][idx * 8]);
    }
#pragma unroll
    for (int r = 0; r < RB; ++r) {
        int idx = r * 256 + tid;
        int row = idx >> 2, kc = (idx & 3) << 3;
        async16(&Bw[(size_t)(n0 + row) * ldb + kc], &lB[0][idx * 8]);
    }
    if (NT > 1) {
#pragma unroll
        for (int r = 0; r < RA; ++r) {
            int idx = r * 256 + tid;
            int row = idx >> 2, kc = (idx & 3) << 3;
            async16(&A[(size_t)(m0 + row) * lda + BK + kc], &lA[1][idx * 8]);
        }
#pragma unroll
        for (int r = 0; r < RB; ++r) {
            int idx = r * 256 + tid;
            int row = idx >> 2, kc = (idx & 3) << 3;
            async16(&Bw[(size_t)(n0 + row) * ldb + BK + kc], &lB[1][idx * 8]);
        }
    }

    for (int t = 0; t < NT; ++t) {
        // barrier A: all waves done reading buf[(t+2)%3] (tile t-1) -> safe to overwrite
        if (t > 0) __builtin_amdgcn_s_barrier();
        if (t + 2 < NT) {
            const int k2 = (t + 2) * BK;
            const int nb = (t + 2) % 3;
#pragma unroll
            for (int r = 0; r < RA; ++r) {
                int idx = r * 256 + tid;
                int row = idx >> 2, kc = (idx & 3) << 3;
                async16(&A[(size_t)(m0 + row) * lda + k2 + kc], &lA[nb][idx * 8]);
            }
#pragma unroll
            for (int r = 0; r < RB; ++r) {
                int idx = r * 256 + tid;
                int row = idx >> 2, kc = (idx & 3) << 3;
                async16(&Bw[(size_t)(n0 + row) * ldb + k2 + kc], &lB[nb][idx * 8]);
            }
            __builtin_amdgcn_s_waitcnt(0x0F70 | (2 * KEEP));  // tile t done; t+1,t+2 in flight
        } else if (t + 1 < NT) {
            __builtin_amdgcn_s_waitcnt(0x0F70 | KEEP);        // tile t done; t+1 in flight
        } else {
            __builtin_amdgcn_s_waitcnt(0x0F70);               // last tile: vmcnt(0)
        }
        __builtin_amdgcn_s_barrier();                          // tile t visible to all waves

        const int cb = t % 3;
        short8 af[FM], bfv[FN];
#pragma unroll
        for (int i = 0; i < FM; ++i)
            af[i] = *reinterpret_cast<const short8*>(&lA[cb][(wm + i * 16 + r16) * BK + quad * 8]);
#pragma unroll
        for (int j = 0; j < FN; ++j)
            bfv[j] = *reinterpret_cast<const short8*>(&lB[cb][(wn + j * 16 + r16) * BK + quad * 8]);
#pragma unroll
        for (int i = 0; i < FM; ++i)
#pragma unroll
            for (int j = 0; j < FN; ++j)
                acc[i][j] = __builtin_amdgcn_mfma_f32_16x16x32_bf16(af[i], bfv[j], acc[i][j], 0, 0, 0);
    }

    const float s = (MODE == 4) ? 1.0f : *s_ptr;
#pragma unroll
    for (int i = 0; i < FM; ++i) {
#pragma unroll
        for (int j = 0; j < FN; ++j) {
#pragma unroll
            for (int r = 0; r < 4; ++r) {
                int gr = m0 + wm + i * 16 + quad * 4 + r;
                int gc = n0 + wn + j * 16 + r16;
                float v = acc[i][j][r] * s;
                if (MODE == 0) {
                    if (gc < DI) o_bf16[(size_t)gr * DI + gc] = __float2bfloat16(v);
                    else o_bf16b[(size_t)gr * DI + (gc - DI)] = __float2bfloat16(v);
                } else if (MODE == 1) {
                    o_bf16[(size_t)gr * N + gc] = __float2bfloat16(v);
                } else if (MODE == 2) {
                    float dt = v + bias[gc];
                    float dc = 0.5f + 0.5f * dt / (1.0f + fabsf(dt));
                    o_u16[(size_t)gr * N + gc] = (unsigned short)rintf(dc * 32768.0f);
                } else if (MODE == 3) {
                    o_f32[(size_t)gr * N + gc] = v + resid[(size_t)gr * N + gc];
                } else {
                    o_f32[(size_t)gr * N + gc] = v;
                }
            }
        }
    }
}

// ---------------- split-K reduce for GEMM2: dbl = bf16(s * sum_z part[z]) ----------------
__global__ __launch_bounds__(256) void k_red(const float* __restrict__ part,
                                             const float* __restrict__ s_ptr,
                                             __hip_bfloat16* __restrict__ dbl) {
    int i = blockIdx.x * 256 + threadIdx.x;  // < NR*DTR
    float s = *s_ptr;
    float acc = 0.f;
#pragma unroll
    for (int z = 0; z < KSLICE; ++z) acc += part[(size_t)z * NR * DTR + i];
    dbl[i] = __float2bfloat16(acc * s);
}

// ---------------- causal depthwise conv (k=4, bf16 in) + bias + squareplus ----------------
__global__ __launch_bounds__(256) void k_conv(const __hip_bfloat16* __restrict__ xc,
                                              const float* __restrict__ cw,
                                              const float* __restrict__ cb,
                                              __hip_bfloat16* __restrict__ xact) {
    int c = blockIdx.x * 256 + threadIdx.x;
    int t0 = blockIdx.y * CHUNK;
    int b = blockIdx.z;
    float w0 = cw[c * 4 + 0], w1 = cw[c * 4 + 1], w2 = cw[c * 4 + 2], w3 = cw[c * 4 + 3];
    float bias = cb[c];
    const __hip_bfloat16* base = xc + (size_t)b * L_ * DI + c;
    float x3 = (t0 - 3 >= 0) ? __bfloat162float(base[(size_t)(t0 - 3) * DI]) : 0.f;
    float x2 = (t0 - 2 >= 0) ? __bfloat162float(base[(size_t)(t0 - 2) * DI]) : 0.f;
    float x1 = (t0 - 1 >= 0) ? __bfloat162float(base[(size_t)(t0 - 1) * DI]) : 0.f;
    for (int t = t0; t < t0 + CHUNK; ++t) {
        float xt = __bfloat162float(base[(size_t)t * DI]);
        float y = x3 * w0 + x2 * w1 + x1 * w2 + xt * w3 + bias;
        xact[((size_t)(b * L_ + t)) * DI + c] = __float2bfloat16(squareplus_f(y));
        x3 = x2; x2 = x1; x1 = xt;
    }
}

// ---------------- chunked linear scan: pass1 (chunk aggregates) ----------------
__global__ __launch_bounds__(256) void k_scan1(const unsigned short* __restrict__ dk,
                                               const __hip_bfloat16* __restrict__ u,
                                               float* __restrict__ cA, float* __restrict__ cB) {
    int c = blockIdx.x * 256 + threadIdx.x;
    int j = blockIdx.y, b = blockIdx.z;
    size_t base = ((size_t)b * L_ + (size_t)j * CHUNK) * DI + c;
    float Ac = 1.f, Bc = 0.f;
    for (int t = 0; t < CHUNK; ++t) {
        float a = dk[base + (size_t)t * DI] * (1.0f / 32768.0f);
        float uv = __bfloat162float(u[base + (size_t)t * DI]);
        Bc = a * Bc + (1.f - a) * uv;
        Ac *= a;
    }
    size_t o = ((size_t)(b * NCHUNK + j)) * DI + c;
    cA[o] = Ac;
    cB[o] = Bc;
}

// ---------------- pass2: prefix (recomputed per block) + final scan + y = h*sp(z) ----------------
__global__ __launch_bounds__(256) void k_scan3(const unsigned short* __restrict__ dk,
                                               const __hip_bfloat16* __restrict__ u,
                                               const __hip_bfloat16* __restrict__ zraw,
                                               const float* __restrict__ cA,
                                               const float* __restrict__ cB,
                                               __hip_bfloat16* __restrict__ y) {
    int c = blockIdx.x * 256 + threadIdx.x;
    int j = blockIdx.y, b = blockIdx.z;
    float h = 0.f;
    for (int jj = 0; jj < j; ++jj) {
        size_t o = ((size_t)(b * NCHUNK + jj)) * DI + c;
        h = cA[o] * h + cB[o];
    }
    size_t base = ((size_t)b * L_ + (size_t)j * CHUNK) * DI + c;
    for (int t = 0; t < CHUNK; ++t) {
        float a = dk[base + (size_t)t * DI] * (1.0f / 32768.0f);
        float uv = __bfloat162float(u[base + (size_t)t * DI]);
        h = a * h + (1.f - a) * uv;
        float zv = squareplus_f(__bfloat162float(zraw[base + (size_t)t * DI]));
        y[base + (size_t)t * DI] = __float2bfloat16(h * zv);
    }
}

// ---------------- launch ----------------
extern "C" void kernel_launch(void* const* d_in, const int* in_sizes, int n_in,
                              void* d_out, int out_size, void* d_ws, size_t ws_size,
                              hipStream_t stream) {
    const float* x      = (const float*)d_in[0];
    const float* gamma  = (const float*)d_in[1];
    const float* step   = (const float*)d_in[2];
    const float* W_in   = (const float*)d_in[3];
    const float* conv_w = (const float*)d_in[4];
    const float* conv_b = (const float*)d_in[5];
    const float* W_x    = (const float*)d_in[6];
    const float* W_dt   = (const float*)d_in[7];
    const float* b_dt   = (const float*)d_in[8];
    const float* W_out  = (const float*)d_in[9];

    char* ws = (char*)d_ws;
    float*          scal = (float*)(ws + OFF_SCAL);
    float*          part = (float*)(ws + OFF_PART);
    __hip_bfloat16* xn   = (__hip_bfloat16*)(ws + OFF_XN);
    __hip_bfloat16* Tin  = (__hip_bfloat16*)(ws + OFF_TIN);
    __hip_bfloat16* Tx   = (__hip_bfloat16*)(ws + OFF_TX);
    __hip_bfloat16* Tdt  = (__hip_bfloat16*)(ws + OFF_TDT);
    __hip_bfloat16* Tout = (__hip_bfloat16*)(ws + OFF_TOUT);
    __hip_bfloat16* xcb  = (__hip_bfloat16*)(ws + OFF_XC);
    float*          p2   = (float*)(ws + OFF_P2);
    __hip_bfloat16* zraw = (__hip_bfloat16*)(ws + OFF_ZSP);
    __hip_bfloat16* xact = (__hip_bfloat16*)(ws + OFF_XACT);
    __hip_bfloat16* dbl  = (__hip_bfloat16*)(ws + OFF_DBL);
    unsigned short* dec  = (unsigned short*)(ws + OFF_DEC);
    float*          cA   = (float*)(ws + OFF_CA);
    float*          cB   = (float*)(ws + OFF_CB);
    __hip_bfloat16* yb   = (__hip_bfloat16*)(ws + OFF_Y);
    float*          out  = (float*)d_out;

    // weight scales + ternary quantization (fused launches)
    k_abs_all<<<dim3(256, 4), 256, 0, stream>>>(W_in, W_x, W_dt, W_out, part);
    k_finalize<<<1, 256, 0, stream>>>(part, scal);
    k_quant_all<<<25600, 256, 0, stream>>>(W_in, W_x, W_dt, W_out, scal, Tin, Tx, Tdt, Tout);

    // norm -> xn (bf16)
    k_norm<<<NR, 256, 0, stream>>>(x, gamma, step, xn);

    // GEMM1: xz = xn @ T_in^T * s ; split -> xc bf16, z raw bf16
    k_gemm<128, 128, 2, 2, 0><<<dim3((2 * DI) / 128, NR / 128), 256, 0, stream>>>(
        xn, Tin, NR, 2 * DI, DM, DM, DM, scal + 0, nullptr, xcb, zraw, nullptr, nullptr, nullptr);

    // conv + bias + squareplus -> xact (bf16)
    k_conv<<<dim3(DI / 256, L_ / CHUNK, B_), 256, 0, stream>>>(xcb, conv_w, conv_b, xact);

    // GEMM2 (split-K): p2[z] = xact[:, z*256:(z+1)*256] @ T_x[:64, ...]^T
    k_gemm<64, 64, 2, 2, 4><<<dim3(1, NR / 64, KSLICE), 256, 0, stream>>>(
        xact, Tx, NR, DTR, DI / KSLICE, DI, DI, nullptr, p2, nullptr, nullptr, nullptr, nullptr, nullptr);
    k_red<<<(NR * DTR) / 256, 256, 0, stream>>>(p2, scal + 1, dbl);

    // GEMM3: dt = dbl @ T_dt^T * s + b_dt -> sigmoid -> dyadic u16 decay
    k_gemm<128, 128, 2, 2, 2><<<dim3(DI / 128, NR / 128), 256, 0, stream>>>(
        dbl, Tdt, NR, DI, DTR, DTR, DTR, scal + 2, nullptr, nullptr, nullptr, dec, b_dt, nullptr);

    // scan (2 passes), pass2 recomputes prefix + fuses y = h * squareplus(z)
    k_scan1<<<dim3(DI / 256, NCHUNK, B_), 256, 0, stream>>>(dec, xact, cA, cB);
    k_scan3<<<dim3(DI / 256, NCHUNK, B_), 256, 0, stream>>>(dec, xact, zraw, cA, cB, yb);

    // GEMM4: out = y @ T_out^T * s + residual
    k_gemm<128, 128, 2, 2, 3><<<dim3(DM / 128, NR / 128), 256, 0, stream>>>(
        yb, Tout, NR, DM, DI, DI, DI, scal + 3, out, nullptr, nullptr, nullptr, nullptr, x);

    (void)in_sizes; (void)n_in; (void)out_size; (void)ws_size;
}

// Round 5
// 376.966 us; speedup vs baseline: 1.5492x; 1.1056x over previous
//
#include <hip/hip_runtime.h>
#include <hip/hip_bf16.h>

#define B_ 4
#define L_ 2048
#define DM 1024
#define DI 2048
#define NR (B_ * L_)   // 8192 rows
#define DTR 64
#define NCHUNK 32
#define CHUNK 64
#define CCONV 64
#define KSLICE 8       // split-K slices for GEMM2

typedef __attribute__((ext_vector_type(8))) short short8;
typedef __attribute__((ext_vector_type(4))) float floatx4;

// ---------------- workspace layout (bytes) ----------------
static constexpr size_t OFF_SCAL = 0;                                    // 4 f32 scales
static constexpr size_t OFF_PART = 256;                                  // 4*256 f32 partials
static constexpr size_t OFF_XN   = 4608;                                 // xn bf16 [NR,DM]
static constexpr size_t OFF_TIN  = OFF_XN   + (size_t)NR * DM * 2;       // T_in bf16 [4096,1024]
static constexpr size_t OFF_TX   = OFF_TIN  + (size_t)2 * DI * DM * 2;   // T_x bf16 [64,2048]
static constexpr size_t OFF_TDT  = OFF_TX   + (size_t)DTR * DI * 2;      // T_dt bf16 [2048,64]
static constexpr size_t OFF_TOUT = OFF_TDT  + (size_t)DI * DTR * 2;      // T_out bf16 [1024,2048]
static constexpr size_t OFF_XC   = OFF_TOUT + (size_t)DM * DI * 2;       // xc bf16 [NR,DI]
static constexpr size_t OFF_P2   = OFF_XC   + (size_t)NR * DI * 2;       // GEMM2 f32 partials [8,NR,64]
static constexpr size_t OFF_ZSP  = OFF_XC   + (size_t)NR * DI * 4;       // z raw bf16 [NR,DI]
static constexpr size_t OFF_XACT = OFF_ZSP  + (size_t)NR * DI * 2;       // sp(conv) bf16 [NR,DI]
static constexpr size_t OFF_DBL  = OFF_XACT + (size_t)NR * DI * 2;       // dbl bf16 [NR,64]
static constexpr size_t OFF_DEC  = OFF_DBL  + (size_t)NR * DTR * 2;      // decay u16 [NR,DI]
static constexpr size_t OFF_CA   = OFF_DEC  + (size_t)NR * DI * 2;       // chunk A f32 [B,32,DI]
static constexpr size_t OFF_CB   = OFF_CA   + (size_t)B_ * NCHUNK * DI * 4;
static constexpr size_t OFF_Y    = OFF_CB   + (size_t)B_ * NCHUNK * DI * 4; // y bf16 [NR,DI]

// ---------------- async global->LDS (16B per lane, wave-uniform base rule) ----------------
__device__ __forceinline__ void async16(const void* g, void* l) {
    __builtin_amdgcn_global_load_lds(
        (const __attribute__((address_space(1))) unsigned int*)g,
        (__attribute__((address_space(3))) unsigned int*)l, 16, 0, 0);
}

// ---------------- scalar math (bit-faithful to reference) ----------------
__device__ __forceinline__ float pow2scale(float var) {
    float v = var + 1e-9f;
    float s = 1.0f;
    if (v >= 4.0f)     s = 0.5f;
    if (v >= 16.0f)    s = 0.25f;
    if (v >= 64.0f)    s = 0.125f;
    if (v >= 256.0f)   s = 0.0625f;
    if (v >= 1024.0f)  s = 0.03125f;
    if (v >= 4096.0f)  s = 0.015625f;
    if (v >= 16384.0f) s = 0.0078125f;
    if (v >= 65536.0f) s = 0.00390625f;
    if (v < 1.0f)    s = 1.0f;
    if (v < 0.25f)   s = 2.0f;
    if (v < 0.0625f) s = 4.0f;
    return s;
}

// NOTE: must stay bit-faithful — the reference's Newton rsqrt genuinely diverges
// for y=x^2+4 in (12,16] (seed 0.5, clip to 1e-6 -> sp(x)=x/2 there). Do NOT
// replace with true rsqrt.
__device__ __forceinline__ float squareplus_f(float x) {
    float y = fminf(fmaxf(x * x + 4.0f, 1e-6f), 1e6f);
    float r = (y > 16.0f) ? 0.125f : 0.5f;
    if (y > 64.0f)  r = 0.0625f;
    if (y > 256.0f) r = 0.03125f;
    if (y < 4.0f)   r = 1.0f;
    if (y < 1.0f)   r = 2.0f;
    if (y < 0.25f)  r = 4.0f;
#pragma unroll
    for (int i = 0; i < 3; ++i) {
        r = r * (1.5f - 0.5f * y * r * r);
        r = fminf(fmaxf(r, 1e-6f), 1e3f);
    }
    float s = fminf(fmaxf(y * r, 0.0f), 1e3f);
    return 0.5f * (x + s);
}

__device__ __forceinline__ float block_reduce_sum(float v) {
    __shared__ float sm[4];
#pragma unroll
    for (int o = 32; o > 0; o >>= 1) v += __shfl_down(v, o, 64);
    int w = threadIdx.x >> 6;
    __syncthreads();
    if ((threadIdx.x & 63) == 0) sm[w] = v;
    __syncthreads();
    return (sm[0] + sm[1]) + (sm[2] + sm[3]);
}

// ---------------- fused weight-scale partials (all 4 weights, one launch, float4) ----------------
__global__ __launch_bounds__(256) void k_abs_all(const float* __restrict__ W0,
                                                 const float* __restrict__ W1,
                                                 const float* __restrict__ W2,
                                                 const float* __restrict__ W3,
                                                 float* __restrict__ part) {
    const int w = blockIdx.y;
    const float* W = (w == 0) ? W0 : (w == 1) ? W1 : (w == 2) ? W2 : W3;
    const int n4 = ((w == 0) ? 2 * DI * DM : (w == 1) ? 96 * DI : (w == 2) ? DI * DTR : DM * DI) / 4;
    const float4* W4 = (const float4*)W;
    float s = 0.f;
    for (int i = blockIdx.x * 256 + threadIdx.x; i < n4; i += 256 * 256) {
        float4 v = W4[i];
        s += fabsf(v.x) + fabsf(v.y) + fabsf(v.z) + fabsf(v.w);
    }
    float t = block_reduce_sum(s);
    if (threadIdx.x == 0) part[w * 256 + blockIdx.x] = t;
}

__global__ __launch_bounds__(256) void k_finalize(const float* __restrict__ part,
                                                  float* __restrict__ scal) {
    const float counts[4] = {(float)(2 * DI * DM), (float)(96 * DI),
                             (float)(DI * DTR), (float)(DM * DI)};
    for (int w = 0; w < 4; ++w) {
        float s = block_reduce_sum(part[w * 256 + threadIdx.x]);
        if (threadIdx.x == 0) scal[w] = s / counts[w] + 1e-8f;
    }
}

// ---------------- fused ternary quantization (float4 in, 4x bf16 out per thread) ----------------
// block segments (1024 elems/block): W_in 4096 | W_x[:64] 128 | W_dt 128 | W_out 2048 = 6400
__global__ __launch_bounds__(256) void k_quant_all(
    const float* __restrict__ W0, const float* __restrict__ W1,
    const float* __restrict__ W2, const float* __restrict__ W3,
    const float* __restrict__ scal,
    __hip_bfloat16* __restrict__ T0, __hip_bfloat16* __restrict__ T1,
    __hip_bfloat16* __restrict__ T2, __hip_bfloat16* __restrict__ T3) {
    int b = blockIdx.x;
    const float* W; const float* sp; __hip_bfloat16* T; int off;
    if (b < 4096)      { W = W0; sp = scal + 0; T = T0; off = b; }
    else if (b < 4224) { W = W1; sp = scal + 1; T = T1; off = b - 4096; }
    else if (b < 4352) { W = W2; sp = scal + 2; T = T2; off = b - 4224; }
    else               { W = W3; sp = scal + 3; T = T3; off = b - 4352; }
    int i = off * 1024 + threadIdx.x * 4;
    float inv = 1.0f / (*sp);
    float4 v = *(const float4*)(W + i);
    __hip_bfloat16 t[4];
    t[0] = __float2bfloat16(fmaxf(-1.0f, fminf(1.0f, rintf(v.x * inv))));
    t[1] = __float2bfloat16(fmaxf(-1.0f, fminf(1.0f, rintf(v.y * inv))));
    t[2] = __float2bfloat16(fmaxf(-1.0f, fminf(1.0f, rintf(v.z * inv))));
    t[3] = __float2bfloat16(fmaxf(-1.0f, fminf(1.0f, rintf(v.w * inv))));
    *reinterpret_cast<uint2*>(&T[i]) = *reinterpret_cast<uint2*>(t);
}

// ---------------- bitshift_norm (one float4 read, registers reused) ----------------
__global__ __launch_bounds__(256) void k_norm(const float* __restrict__ x,
                                              const float* __restrict__ gamma,
                                              const float* __restrict__ step,
                                              __hip_bfloat16* __restrict__ xn) {
    int row = blockIdx.x;
    int tid = threadIdx.x;
    float4 v4 = ((const float4*)(x + (size_t)row * DM))[tid];
    float s = (v4.x + v4.y) + (v4.z + v4.w);
    float mean = block_reduce_sum(s) * (1.0f / DM);
    float d0 = v4.x - mean, d1 = v4.y - mean, d2 = v4.z - mean, d3 = v4.w - mean;
    float vv = d0 * d0 + d1 * d1 + d2 * d2 + d3 * d3;
    float var = block_reduce_sum(vv) * (1.0f / DM);
    float sc = pow2scale(var) * step[0];
    float4 g = ((const float4*)gamma)[tid];
    __hip_bfloat16 t[4];
    t[0] = __float2bfloat16(d0 * sc * g.x);
    t[1] = __float2bfloat16(d1 * sc * g.y);
    t[2] = __float2bfloat16(d2 * sc * g.z);
    t[3] = __float2bfloat16(d3 * sc * g.w);
    *reinterpret_cast<uint2*>(&xn[(size_t)row * DM + tid * 4]) = *reinterpret_cast<uint2*>(t);
}

// ---------------- MFMA GEMM, depth-2 pipeline (3 LDS buffers): C = A[M,K] @ B[N,K]^T ----------------
// MODE 0: xz epilogue  (col<DI -> xc bf16 via o_bf16 ; col>=DI -> raw z bf16 via o_bf16b)
// MODE 1: plain bf16 out
// MODE 2: dt -> sigmoid -> dyadic u16 decay
// MODE 3: f32 out + residual
// MODE 4: f32 partial (split-K over blockIdx.z, no scale)
template <int BM, int BN, int WR, int WC, int MODE>
__global__ __launch_bounds__(256) void k_gemm(
    const __hip_bfloat16* __restrict__ A, const __hip_bfloat16* __restrict__ Bw,
    int M, int N, int K, int lda, int ldb, const float* __restrict__ s_ptr,
    float* __restrict__ o_f32, __hip_bfloat16* __restrict__ o_bf16,
    __hip_bfloat16* __restrict__ o_bf16b, unsigned short* __restrict__ o_u16,
    const float* __restrict__ bias, const float* __restrict__ resid) {
    constexpr int BK = 32;
    constexpr int FM = BM / (WR * 16), FN = BN / (WC * 16);
    constexpr int RA = (BM * BK) / (256 * 8);  // async-16B rounds for A tile
    constexpr int RB = (BN * BK) / (256 * 8);
    constexpr int KEEP = RA + RB;              // loads in flight per thread per tile
    __shared__ __align__(16) short lA[3][BM * BK];
    __shared__ __align__(16) short lB[3][BN * BK];
    const int tid = threadIdx.x;
    const int lane = tid & 63, wid = tid >> 6;
    const int wm = (wid / WC) * (BM / WR);
    const int wn = (wid % WC) * (BN / WC);
    const int r16 = lane & 15, quad = lane >> 4;

    // split-K slice offset
    if (MODE == 4) {
        A  += (size_t)blockIdx.z * K;
        Bw += (size_t)blockIdx.z * K;
        o_f32 += (size_t)blockIdx.z * M * N;
    }

    // XCD-aware swizzle: contiguous strip of N-tiles per XCD
    int nx = gridDim.x;
    int bx = blockIdx.x, by = blockIdx.y;
    if ((nx & 7) == 0 && nx >= 8) {
        int bid = by * nx + bx;
        int xcd = bid & 7, idx = bid >> 3;
        int npx = nx >> 3;
        bx = xcd * npx + (idx % npx);
        by = idx / npx;
    }
    const int m0 = by * BM, n0 = bx * BN;

    floatx4 acc[FM][FN] = {};
    const int NT = K / BK;

    // prologue: prefetch tiles 0 and 1
#pragma unroll
    for (int r = 0; r < RA; ++r) {
        int idx = r * 256 + tid;
        int row = idx >> 2, kc = (idx & 3) << 3;
        async16(&A[(size_t)(m0 + row) * lda + kc], &lA[0][idx * 8]);
    }
#pragma unroll
    for (int r = 0; r < RB; ++r) {
        int idx = r * 256 + tid;
        int row = idx >> 2, kc = (idx & 3) << 3;
        async16(&Bw[(size_t)(n0 + row) * ldb + kc], &lB[0][idx * 8]);
    }
    if (NT > 1) {
#pragma unroll
        for (int r = 0; r < RA; ++r) {
            int idx = r * 256 + tid;
            int row = idx >> 2, kc = (idx & 3) << 3;
            async16(&A[(size_t)(m0 + row) * lda + BK + kc], &lA[1][idx * 8]);
        }
#pragma unroll
        for (int r = 0; r < RB; ++r) {
            int idx = r * 256 + tid;
            int row = idx >> 2, kc = (idx & 3) << 3;
            async16(&Bw[(size_t)(n0 + row) * ldb + BK + kc], &lB[1][idx * 8]);
        }
    }

    for (int t = 0; t < NT; ++t) {
        // barrier A: all waves done reading buf[(t+2)%3] (tile t-1) -> safe to overwrite
        if (t > 0) __builtin_amdgcn_s_barrier();
        if (t + 2 < NT) {
            const int k2 = (t + 2) * BK;
            const int nb = (t + 2) % 3;
#pragma unroll
            for (int r = 0; r < RA; ++r) {
                int idx = r * 256 + tid;
                int row = idx >> 2, kc = (idx & 3) << 3;
                async16(&A[(size_t)(m0 + row) * lda + k2 + kc], &lA[nb][idx * 8]);
            }
#pragma unroll
            for (int r = 0; r < RB; ++r) {
                int idx = r * 256 + tid;
                int row = idx >> 2, kc = (idx & 3) << 3;
                async16(&Bw[(size_t)(n0 + row) * ldb + k2 + kc], &lB[nb][idx * 8]);
            }
            __builtin_amdgcn_s_waitcnt(0x0F70 | (2 * KEEP));  // tile t done; t+1,t+2 in flight
        } else if (t + 1 < NT) {
            __builtin_amdgcn_s_waitcnt(0x0F70 | KEEP);        // tile t done; t+1 in flight
        } else {
            __builtin_amdgcn_s_waitcnt(0x0F70);               // last tile: vmcnt(0)
        }
        __builtin_amdgcn_s_barrier();                          // tile t visible to all waves

        const int cb = t % 3;
        short8 af[FM], bfv[FN];
#pragma unroll
        for (int i = 0; i < FM; ++i)
            af[i] = *reinterpret_cast<const short8*>(&lA[cb][(wm + i * 16 + r16) * BK + quad * 8]);
#pragma unroll
        for (int j = 0; j < FN; ++j)
            bfv[j] = *reinterpret_cast<const short8*>(&lB[cb][(wn + j * 16 + r16) * BK + quad * 8]);
#pragma unroll
        for (int i = 0; i < FM; ++i)
#pragma unroll
            for (int j = 0; j < FN; ++j)
                acc[i][j] = __builtin_amdgcn_mfma_f32_16x16x32_bf16(af[i], bfv[j], acc[i][j], 0, 0, 0);
    }

    const float s = (MODE == 4) ? 1.0f : *s_ptr;
#pragma unroll
    for (int i = 0; i < FM; ++i) {
#pragma unroll
        for (int j = 0; j < FN; ++j) {
#pragma unroll
            for (int r = 0; r < 4; ++r) {
                int gr = m0 + wm + i * 16 + quad * 4 + r;
                int gc = n0 + wn + j * 16 + r16;
                float v = acc[i][j][r] * s;
                if (MODE == 0) {
                    if (gc < DI) o_bf16[(size_t)gr * DI + gc] = __float2bfloat16(v);
                    else o_bf16b[(size_t)gr * DI + (gc - DI)] = __float2bfloat16(v);
                } else if (MODE == 1) {
                    o_bf16[(size_t)gr * N + gc] = __float2bfloat16(v);
                } else if (MODE == 2) {
                    float dt = v + bias[gc];
                    float dc = 0.5f + 0.5f * dt / (1.0f + fabsf(dt));
                    o_u16[(size_t)gr * N + gc] = (unsigned short)rintf(dc * 32768.0f);
                } else if (MODE == 3) {
                    o_f32[(size_t)gr * N + gc] = v + resid[(size_t)gr * N + gc];
                } else {
                    o_f32[(size_t)gr * N + gc] = v;
                }
            }
        }
    }
}

// ---------------- split-K reduce for GEMM2: dbl = bf16(s * sum_z part[z]) ----------------
__global__ __launch_bounds__(256) void k_red(const float* __restrict__ part,
                                             const float* __restrict__ s_ptr,
                                             __hip_bfloat16* __restrict__ dbl) {
    int i = blockIdx.x * 256 + threadIdx.x;  // < NR*DTR
    float s = *s_ptr;
    float acc = 0.f;
#pragma unroll
    for (int z = 0; z < KSLICE; ++z) acc += part[(size_t)z * NR * DTR + i];
    dbl[i] = __float2bfloat16(acc * s);
}

// ---------------- causal depthwise conv (k=4, bf16 in) + bias + squareplus ----------------
__global__ __launch_bounds__(256) void k_conv(const __hip_bfloat16* __restrict__ xc,
                                              const float* __restrict__ cw,
                                              const float* __restrict__ cb,
                                              __hip_bfloat16* __restrict__ xact) {
    int c = blockIdx.x * 256 + threadIdx.x;
    int t0 = blockIdx.y * CCONV;
    int b = blockIdx.z;
    float w0 = cw[c * 4 + 0], w1 = cw[c * 4 + 1], w2 = cw[c * 4 + 2], w3 = cw[c * 4 + 3];
    float bias = cb[c];
    const __hip_bfloat16* base = xc + (size_t)b * L_ * DI + c;
    float x3 = (t0 - 3 >= 0) ? __bfloat162float(base[(size_t)(t0 - 3) * DI]) : 0.f;
    float x2 = (t0 - 2 >= 0) ? __bfloat162float(base[(size_t)(t0 - 2) * DI]) : 0.f;
    float x1 = (t0 - 1 >= 0) ? __bfloat162float(base[(size_t)(t0 - 1) * DI]) : 0.f;
    for (int t = t0; t < t0 + CCONV; ++t) {
        float xt = __bfloat162float(base[(size_t)t * DI]);
        float y = x3 * w0 + x2 * w1 + x1 * w2 + xt * w3 + bias;
        xact[((size_t)(b * L_ + t)) * DI + c] = __float2bfloat16(squareplus_f(y));
        x3 = x2; x2 = x1; x1 = xt;
    }
}

// ---------------- chunked linear scan: pass1 (chunk aggregates) ----------------
__global__ __launch_bounds__(256) void k_scan1(const unsigned short* __restrict__ dk,
                                               const __hip_bfloat16* __restrict__ u,
                                               float* __restrict__ cA, float* __restrict__ cB) {
    int c = blockIdx.x * 256 + threadIdx.x;
    int j = blockIdx.y, b = blockIdx.z;
    size_t base = ((size_t)b * L_ + (size_t)j * CHUNK) * DI + c;
    float Ac = 1.f, Bc = 0.f;
    for (int t = 0; t < CHUNK; ++t) {
        float a = dk[base + (size_t)t * DI] * (1.0f / 32768.0f);
        float uv = __bfloat162float(u[base + (size_t)t * DI]);
        Bc = a * Bc + (1.f - a) * uv;
        Ac *= a;
    }
    size_t o = ((size_t)(b * NCHUNK + j)) * DI + c;
    cA[o] = Ac;
    cB[o] = Bc;
}

// ---------------- pass2: prefix (recomputed per block) + final scan + y = h*sp(z) ----------------
__global__ __launch_bounds__(256) void k_scan3(const unsigned short* __restrict__ dk,
                                               const __hip_bfloat16* __restrict__ u,
                                               const __hip_bfloat16* __restrict__ zraw,
                                               const float* __restrict__ cA,
                                               const float* __restrict__ cB,
                                               __hip_bfloat16* __restrict__ y) {
    int c = blockIdx.x * 256 + threadIdx.x;
    int j = blockIdx.y, b = blockIdx.z;
    float h = 0.f;
    for (int jj = 0; jj < j; ++jj) {
        size_t o = ((size_t)(b * NCHUNK + jj)) * DI + c;
        h = cA[o] * h + cB[o];
    }
    size_t base = ((size_t)b * L_ + (size_t)j * CHUNK) * DI + c;
    for (int t = 0; t < CHUNK; ++t) {
        float a = dk[base + (size_t)t * DI] * (1.0f / 32768.0f);
        float uv = __bfloat162float(u[base + (size_t)t * DI]);
        h = a * h + (1.f - a) * uv;
        float zv = squareplus_f(__bfloat162float(zraw[base + (size_t)t * DI]));
        y[base + (size_t)t * DI] = __float2bfloat16(h * zv);
    }
}

// ---------------- launch ----------------
extern "C" void kernel_launch(void* const* d_in, const int* in_sizes, int n_in,
                              void* d_out, int out_size, void* d_ws, size_t ws_size,
                              hipStream_t stream) {
    const float* x      = (const float*)d_in[0];
    const float* gamma  = (const float*)d_in[1];
    const float* step   = (const float*)d_in[2];
    const float* W_in   = (const float*)d_in[3];
    const float* conv_w = (const float*)d_in[4];
    const float* conv_b = (const float*)d_in[5];
    const float* W_x    = (const float*)d_in[6];
    const float* W_dt   = (const float*)d_in[7];
    const float* b_dt   = (const float*)d_in[8];
    const float* W_out  = (const float*)d_in[9];

    char* ws = (char*)d_ws;
    float*          scal = (float*)(ws + OFF_SCAL);
    float*          part = (float*)(ws + OFF_PART);
    __hip_bfloat16* xn   = (__hip_bfloat16*)(ws + OFF_XN);
    __hip_bfloat16* Tin  = (__hip_bfloat16*)(ws + OFF_TIN);
    __hip_bfloat16* Tx   = (__hip_bfloat16*)(ws + OFF_TX);
    __hip_bfloat16* Tdt  = (__hip_bfloat16*)(ws + OFF_TDT);
    __hip_bfloat16* Tout = (__hip_bfloat16*)(ws + OFF_TOUT);
    __hip_bfloat16* xcb  = (__hip_bfloat16*)(ws + OFF_XC);
    float*          p2   = (float*)(ws + OFF_P2);
    __hip_bfloat16* zraw = (__hip_bfloat16*)(ws + OFF_ZSP);
    __hip_bfloat16* xact = (__hip_bfloat16*)(ws + OFF_XACT);
    __hip_bfloat16* dbl  = (__hip_bfloat16*)(ws + OFF_DBL);
    unsigned short* dec  = (unsigned short*)(ws + OFF_DEC);
    float*          cA   = (float*)(ws + OFF_CA);
    float*          cB   = (float*)(ws + OFF_CB);
    __hip_bfloat16* yb   = (__hip_bfloat16*)(ws + OFF_Y);
    float*          out  = (float*)d_out;

    // weight scales + ternary quantization (fused, vectorized)
    k_abs_all<<<dim3(256, 4), 256, 0, stream>>>(W_in, W_x, W_dt, W_out, part);
    k_finalize<<<1, 256, 0, stream>>>(part, scal);
    k_quant_all<<<6400, 256, 0, stream>>>(W_in, W_x, W_dt, W_out, scal, Tin, Tx, Tdt, Tout);

    // norm -> xn (bf16)
    k_norm<<<NR, 256, 0, stream>>>(x, gamma, step, xn);

    // GEMM1: xz = xn @ T_in^T * s ; split -> xc bf16, z raw bf16
    k_gemm<128, 128, 2, 2, 0><<<dim3((2 * DI) / 128, NR / 128), 256, 0, stream>>>(
        xn, Tin, NR, 2 * DI, DM, DM, DM, scal + 0, nullptr, xcb, zraw, nullptr, nullptr, nullptr);

    // conv + bias + squareplus -> xact (bf16)
    k_conv<<<dim3(DI / 256, L_ / CCONV, B_), 256, 0, stream>>>(xcb, conv_w, conv_b, xact);

    // GEMM2 (split-K): p2[z] = xact[:, z*256:(z+1)*256] @ T_x[:64, ...]^T
    k_gemm<64, 64, 2, 2, 4><<<dim3(1, NR / 64, KSLICE), 256, 0, stream>>>(
        xact, Tx, NR, DTR, DI / KSLICE, DI, DI, nullptr, p2, nullptr, nullptr, nullptr, nullptr, nullptr);
    k_red<<<(NR * DTR) / 256, 256, 0, stream>>>(p2, scal + 1, dbl);

    // GEMM3: dt = dbl @ T_dt^T * s + b_dt -> sigmoid -> dyadic u16 decay
    k_gemm<128, 128, 2, 2, 2><<<dim3(DI / 128, NR / 128), 256, 0, stream>>>(
        dbl, Tdt, NR, DI, DTR, DTR, DTR, scal + 2, nullptr, nullptr, nullptr, dec, b_dt, nullptr);

    // scan (2 passes, 64-step chunks), pass2 recomputes prefix + fuses y = h * squareplus(z)
    k_scan1<<<dim3(DI / 256, NCHUNK, B_), 256, 0, stream>>>(dec, xact, cA, cB);
    k_scan3<<<dim3(DI / 256, NCHUNK, B_), 256, 0, stream>>>(dec, xact, zraw, cA, cB, yb);

    // GEMM4: out = y @ T_out^T * s + residual  (BM=64/BN=128 -> 1024 blocks, 4/CU)
    k_gemm<64, 128, 2, 2, 3><<<dim3(DM / 128, NR / 64), 256, 0, stream>>>(
        yb, Tout, NR, DM, DI, DI, DI, scal + 3, out, nullptr, nullptr, nullptr, nullptr, x);

    (void)in_sizes; (void)n_in; (void)out_size; (void)ws_size;
}

// Round 6
// 343.609 us; speedup vs baseline: 1.6996x; 1.0971x over previous
//
#include <hip/hip_runtime.h>
#include <hip/hip_bf16.h>

#define B_ 4
#define L_ 2048
#define DM 1024
#define DI 2048
#define NR (B_ * L_)   // 8192 rows
#define DTR 64
#define NCHUNK 32
#define CHUNK 64
#define CCONV 64
#define KSLICE 8       // split-K slices for GEMM2

typedef __attribute__((ext_vector_type(8))) short short8;
typedef __attribute__((ext_vector_type(4))) float floatx4;
typedef __attribute__((ext_vector_type(4))) int int4v;

// ---------------- workspace layout (bytes) ----------------
static constexpr size_t OFF_SCAL = 0;                                    // 4 f32 scales
static constexpr size_t OFF_PART = 256;                                  // 4*256 f32 partials
static constexpr size_t OFF_XN   = 4608;                                 // xn i8 [NR,DM] (8 MB of 16 MB region)
static constexpr size_t OFF_TIN  = OFF_XN   + (size_t)NR * DM * 2;       // T_in i8 [4096,1024] (4 MB of 8 MB region)
static constexpr size_t OFF_TX   = OFF_TIN  + (size_t)2 * DI * DM * 2;   // T_x bf16 [64,2048]
static constexpr size_t OFF_TDT  = OFF_TX   + (size_t)DTR * DI * 2;      // T_dt bf16 [2048,64]
static constexpr size_t OFF_TOUT = OFF_TDT  + (size_t)DI * DTR * 2;      // T_out bf16 [1024,2048]
static constexpr size_t OFF_XC   = OFF_TOUT + (size_t)DM * DI * 2;       // xc bf16 [NR,DI]
static constexpr size_t OFF_P2   = OFF_XC   + (size_t)NR * DI * 2;       // GEMM2 f32 partials [8,NR,64]
static constexpr size_t OFF_ZSP  = OFF_XC   + (size_t)NR * DI * 4;       // z raw bf16 [NR,DI]
static constexpr size_t OFF_XACT = OFF_ZSP  + (size_t)NR * DI * 2;       // sp(conv) bf16 [NR,DI]
static constexpr size_t OFF_DBL  = OFF_XACT + (size_t)NR * DI * 2;       // dbl bf16 [NR,64]
static constexpr size_t OFF_DEC  = OFF_DBL  + (size_t)NR * DTR * 2;      // decay u16 [NR,DI]
static constexpr size_t OFF_CA   = OFF_DEC  + (size_t)NR * DI * 2;       // chunk A f32 [B,32,DI]
static constexpr size_t OFF_CB   = OFF_CA   + (size_t)B_ * NCHUNK * DI * 4;
static constexpr size_t OFF_Y    = OFF_CB   + (size_t)B_ * NCHUNK * DI * 4; // y bf16 [NR,DI]
static constexpr size_t OFF_SROW = OFF_Y    + (size_t)NR * DI * 2;       // per-row xn scale f32 [NR]

// ---------------- async global->LDS (16B per lane, wave-uniform base rule) ----------------
__device__ __forceinline__ void async16(const void* g, void* l) {
    __builtin_amdgcn_global_load_lds(
        (const __attribute__((address_space(1))) unsigned int*)g,
        (__attribute__((address_space(3))) unsigned int*)l, 16, 0, 0);
}

// ---------------- scalar math (bit-faithful to reference) ----------------
__device__ __forceinline__ float pow2scale(float var) {
    float v = var + 1e-9f;
    float s = 1.0f;
    if (v >= 4.0f)     s = 0.5f;
    if (v >= 16.0f)    s = 0.25f;
    if (v >= 64.0f)    s = 0.125f;
    if (v >= 256.0f)   s = 0.0625f;
    if (v >= 1024.0f)  s = 0.03125f;
    if (v >= 4096.0f)  s = 0.015625f;
    if (v >= 16384.0f) s = 0.0078125f;
    if (v >= 65536.0f) s = 0.00390625f;
    if (v < 1.0f)    s = 1.0f;
    if (v < 0.25f)   s = 2.0f;
    if (v < 0.0625f) s = 4.0f;
    return s;
}

// NOTE: must stay bit-faithful — the reference's Newton rsqrt genuinely diverges
// for y=x^2+4 in (12,16] (seed 0.5, clip to 1e-6 -> sp(x)=x/2 there). Do NOT
// replace with true rsqrt.
__device__ __forceinline__ float squareplus_f(float x) {
    float y = fminf(fmaxf(x * x + 4.0f, 1e-6f), 1e6f);
    float r = (y > 16.0f) ? 0.125f : 0.5f;
    if (y > 64.0f)  r = 0.0625f;
    if (y > 256.0f) r = 0.03125f;
    if (y < 4.0f)   r = 1.0f;
    if (y < 1.0f)   r = 2.0f;
    if (y < 0.25f)  r = 4.0f;
#pragma unroll
    for (int i = 0; i < 3; ++i) {
        r = r * (1.5f - 0.5f * y * r * r);
        r = fminf(fmaxf(r, 1e-6f), 1e3f);
    }
    float s = fminf(fmaxf(y * r, 0.0f), 1e3f);
    return 0.5f * (x + s);
}

__device__ __forceinline__ float block_reduce_sum(float v) {
    __shared__ float sm[4];
#pragma unroll
    for (int o = 32; o > 0; o >>= 1) v += __shfl_down(v, o, 64);
    int w = threadIdx.x >> 6;
    __syncthreads();
    if ((threadIdx.x & 63) == 0) sm[w] = v;
    __syncthreads();
    return (sm[0] + sm[1]) + (sm[2] + sm[3]);
}

__device__ __forceinline__ float block_reduce_max(float v) {
    __shared__ float smx[4];
#pragma unroll
    for (int o = 32; o > 0; o >>= 1) v = fmaxf(v, __shfl_down(v, o, 64));
    int w = threadIdx.x >> 6;
    __syncthreads();
    if ((threadIdx.x & 63) == 0) smx[w] = v;
    __syncthreads();
    return fmaxf(fmaxf(smx[0], smx[1]), fmaxf(smx[2], smx[3]));
}

// ---------------- fused weight-scale partials (all 4 weights, one launch, float4) ----------------
__global__ __launch_bounds__(256) void k_abs_all(const float* __restrict__ W0,
                                                 const float* __restrict__ W1,
                                                 const float* __restrict__ W2,
                                                 const float* __restrict__ W3,
                                                 float* __restrict__ part) {
    const int w = blockIdx.y;
    const float* W = (w == 0) ? W0 : (w == 1) ? W1 : (w == 2) ? W2 : W3;
    const int n4 = ((w == 0) ? 2 * DI * DM : (w == 1) ? 96 * DI : (w == 2) ? DI * DTR : DM * DI) / 4;
    const float4* W4 = (const float4*)W;
    float s = 0.f;
    for (int i = blockIdx.x * 256 + threadIdx.x; i < n4; i += 256 * 256) {
        float4 v = W4[i];
        s += fabsf(v.x) + fabsf(v.y) + fabsf(v.z) + fabsf(v.w);
    }
    float t = block_reduce_sum(s);
    if (threadIdx.x == 0) part[w * 256 + blockIdx.x] = t;
}

__global__ __launch_bounds__(256) void k_finalize(const float* __restrict__ part,
                                                  float* __restrict__ scal) {
    const float counts[4] = {(float)(2 * DI * DM), (float)(96 * DI),
                             (float)(DI * DTR), (float)(DM * DI)};
    for (int w = 0; w < 4; ++w) {
        float s = block_reduce_sum(part[w * 256 + threadIdx.x]);
        if (threadIdx.x == 0) scal[w] = s / counts[w] + 1e-8f;
    }
}

// ---------------- fused ternary quantization ----------------
// W_in -> i8 (exact ternary); W_x/W_dt/W_out -> bf16 (exact ternary)
// block segments (1024 elems/block): W_in 4096 | W_x[:64] 128 | W_dt 128 | W_out 2048 = 6400
__global__ __launch_bounds__(256) void k_quant_all(
    const float* __restrict__ W0, const float* __restrict__ W1,
    const float* __restrict__ W2, const float* __restrict__ W3,
    const float* __restrict__ scal,
    signed char* __restrict__ T0, __hip_bfloat16* __restrict__ T1,
    __hip_bfloat16* __restrict__ T2, __hip_bfloat16* __restrict__ T3) {
    int b = blockIdx.x;
    if (b < 4096) {
        int i = b * 1024 + threadIdx.x * 4;
        float inv = 1.0f / scal[0];
        float4 v = *(const float4*)(W0 + i);
        int q0 = (int)fmaxf(-1.0f, fminf(1.0f, rintf(v.x * inv)));
        int q1 = (int)fmaxf(-1.0f, fminf(1.0f, rintf(v.y * inv)));
        int q2 = (int)fmaxf(-1.0f, fminf(1.0f, rintf(v.z * inv)));
        int q3 = (int)fmaxf(-1.0f, fminf(1.0f, rintf(v.w * inv)));
        unsigned int packed = (q0 & 255) | ((q1 & 255) << 8) | ((q2 & 255) << 16) | ((q3 & 255) << 24);
        *reinterpret_cast<unsigned int*>(&T0[i]) = packed;
        return;
    }
    const float* W; const float* sp; __hip_bfloat16* T; int off;
    if (b < 4224)      { W = W1; sp = scal + 1; T = T1; off = b - 4096; }
    else if (b < 4352) { W = W2; sp = scal + 2; T = T2; off = b - 4224; }
    else               { W = W3; sp = scal + 3; T = T3; off = b - 4352; }
    int i = off * 1024 + threadIdx.x * 4;
    float inv = 1.0f / (*sp);
    float4 v = *(const float4*)(W + i);
    __hip_bfloat16 t[4];
    t[0] = __float2bfloat16(fmaxf(-1.0f, fminf(1.0f, rintf(v.x * inv))));
    t[1] = __float2bfloat16(fmaxf(-1.0f, fminf(1.0f, rintf(v.y * inv))));
    t[2] = __float2bfloat16(fmaxf(-1.0f, fminf(1.0f, rintf(v.z * inv))));
    t[3] = __float2bfloat16(fmaxf(-1.0f, fminf(1.0f, rintf(v.w * inv))));
    *reinterpret_cast<uint2*>(&T[i]) = *reinterpret_cast<uint2*>(t);
}

// ---------------- bitshift_norm -> per-row i8 quantized xn + row scale ----------------
__global__ __launch_bounds__(256) void k_norm(const float* __restrict__ x,
                                              const float* __restrict__ gamma,
                                              const float* __restrict__ step,
                                              signed char* __restrict__ xn8,
                                              float* __restrict__ srow) {
    int row = blockIdx.x;
    int tid = threadIdx.x;
    float4 v4 = ((const float4*)(x + (size_t)row * DM))[tid];
    float s = (v4.x + v4.y) + (v4.z + v4.w);
    float mean = block_reduce_sum(s) * (1.0f / DM);
    float d0 = v4.x - mean, d1 = v4.y - mean, d2 = v4.z - mean, d3 = v4.w - mean;
    float vv = d0 * d0 + d1 * d1 + d2 * d2 + d3 * d3;
    float var = block_reduce_sum(vv) * (1.0f / DM);
    float sc = pow2scale(var) * step[0];
    float4 g = ((const float4*)gamma)[tid];
    float w0 = d0 * sc * g.x, w1 = d1 * sc * g.y, w2 = d2 * sc * g.z, w3 = d3 * sc * g.w;
    float am = fmaxf(fmaxf(fabsf(w0), fabsf(w1)), fmaxf(fabsf(w2), fabsf(w3)));
    am = block_reduce_max(am);
    float sr = (am > 0.f) ? am * (1.0f / 127.0f) : 1.0f;
    float inv = 1.0f / sr;
    if (tid == 0) srow[row] = sr;
    int q0 = (int)rintf(w0 * inv), q1 = (int)rintf(w1 * inv);
    int q2 = (int)rintf(w2 * inv), q3 = (int)rintf(w3 * inv);
    unsigned int packed = (q0 & 255) | ((q1 & 255) << 8) | ((q2 & 255) << 16) | ((q3 & 255) << 24);
    ((unsigned int*)xn8)[row * 256 + tid] = packed;
}

// ---------------- GEMM1 (i8, 16x16x64 MFMA), depth-2 pipeline, 3 LDS buffers ----------------
// C = xn8[8192,1024] @ Tin8[4096,1024]^T ; epilogue col<DI -> xc bf16, col>=DI -> z bf16
__global__ __launch_bounds__(256) void k_gemm1_i8(
    const signed char* __restrict__ A, const signed char* __restrict__ Bw,
    const float* __restrict__ s_ptr, const float* __restrict__ srow,
    __hip_bfloat16* __restrict__ o_xc, __hip_bfloat16* __restrict__ o_z) {
    constexpr int BM = 128, BN = 128, BKB = 64;   // 64 bytes/row = K=64 i8
    constexpr int FM = 4, FN = 4;
    constexpr int RA = 2, RB = 2, KEEP = RA + RB; // (128*64)/(256*16) = 2 rounds
    constexpr int K = DM, NT = K / 64;            // 16 K-tiles
    __shared__ __align__(16) signed char lA[3][BM * BKB];
    __shared__ __align__(16) signed char lB[3][BN * BKB];
    const int tid = threadIdx.x;
    const int lane = tid & 63, wid = tid >> 6;
    const int wm = (wid >> 1) * 64;
    const int wn = (wid & 1) * 64;
    const int r16 = lane & 15, quad = lane >> 4;

    int nx = gridDim.x;
    int bx = blockIdx.x, by = blockIdx.y;
    {
        int bid = by * nx + bx;
        int xcd = bid & 7, idx = bid >> 3;
        int npx = nx >> 3;
        bx = xcd * npx + (idx % npx);
        by = idx / npx;
    }
    const int m0 = by * BM, n0 = bx * BN;

    int4v acc[FM][FN] = {};

    // prologue: prefetch tiles 0 and 1
#pragma unroll
    for (int p = 0; p < 2; ++p) {
#pragma unroll
        for (int r = 0; r < RA; ++r) {
            int idx = r * 256 + tid;
            int row = idx >> 2, kc = (idx & 3) << 4;
            async16(&A[(size_t)(m0 + row) * K + p * 64 + kc], &lA[p][idx * 16]);
        }
#pragma unroll
        for (int r = 0; r < RB; ++r) {
            int idx = r * 256 + tid;
            int row = idx >> 2, kc = (idx & 3) << 4;
            async16(&Bw[(size_t)(n0 + row) * K + p * 64 + kc], &lB[p][idx * 16]);
        }
    }

    for (int t = 0; t < NT; ++t) {
        if (t > 0) __builtin_amdgcn_s_barrier();
        if (t + 2 < NT) {
            const int k2 = (t + 2) * 64;
            const int nb = (t + 2) % 3;
#pragma unroll
            for (int r = 0; r < RA; ++r) {
                int idx = r * 256 + tid;
                int row = idx >> 2, kc = (idx & 3) << 4;
                async16(&A[(size_t)(m0 + row) * K + k2 + kc], &lA[nb][idx * 16]);
            }
#pragma unroll
            for (int r = 0; r < RB; ++r) {
                int idx = r * 256 + tid;
                int row = idx >> 2, kc = (idx & 3) << 4;
                async16(&Bw[(size_t)(n0 + row) * K + k2 + kc], &lB[nb][idx * 16]);
            }
            __builtin_amdgcn_s_waitcnt(0x0F70 | (2 * KEEP));
        } else if (t + 1 < NT) {
            __builtin_amdgcn_s_waitcnt(0x0F70 | KEEP);
        } else {
            __builtin_amdgcn_s_waitcnt(0x0F70);
        }
        __builtin_amdgcn_s_barrier();

        const int cb = t % 3;
        int4v af[FM], bfv[FN];
#pragma unroll
        for (int i = 0; i < FM; ++i)
            af[i] = *reinterpret_cast<const int4v*>(&lA[cb][(wm + i * 16 + r16) * BKB + quad * 16]);
#pragma unroll
        for (int j = 0; j < FN; ++j)
            bfv[j] = *reinterpret_cast<const int4v*>(&lB[cb][(wn + j * 16 + r16) * BKB + quad * 16]);
#pragma unroll
        for (int i = 0; i < FM; ++i)
#pragma unroll
            for (int j = 0; j < FN; ++j)
                acc[i][j] = __builtin_amdgcn_mfma_i32_16x16x64_i8(af[i], bfv[j], acc[i][j], 0, 0, 0);
    }

    const float sW = *s_ptr;
#pragma unroll
    for (int i = 0; i < FM; ++i) {
#pragma unroll
        for (int j = 0; j < FN; ++j) {
#pragma unroll
            for (int r = 0; r < 4; ++r) {
                int gr = m0 + wm + i * 16 + quad * 4 + r;
                int gc = n0 + wn + j * 16 + r16;
                float v = (float)acc[i][j][r] * sW * srow[gr];
                if (gc < DI) o_xc[(size_t)gr * DI + gc] = __float2bfloat16(v);
                else         o_z[(size_t)gr * DI + (gc - DI)] = __float2bfloat16(v);
            }
        }
    }
}

// ---------------- MFMA GEMM (bf16), depth-2 pipeline (3 LDS buffers): C = A @ B^T ----------------
// MODE 1: plain bf16 out
// MODE 2: dt -> sigmoid -> dyadic u16 decay
// MODE 3: f32 out + residual
// MODE 4: f32 partial (split-K over blockIdx.z, no scale)
template <int BM, int BN, int WR, int WC, int MODE>
__global__ __launch_bounds__(256) void k_gemm(
    const __hip_bfloat16* __restrict__ A, const __hip_bfloat16* __restrict__ Bw,
    int M, int N, int K, int lda, int ldb, const float* __restrict__ s_ptr,
    float* __restrict__ o_f32, __hip_bfloat16* __restrict__ o_bf16,
    unsigned short* __restrict__ o_u16,
    const float* __restrict__ bias, const float* __restrict__ resid) {
    constexpr int BK = 32;
    constexpr int FM = BM / (WR * 16), FN = BN / (WC * 16);
    constexpr int RA = (BM * BK) / (256 * 8);
    constexpr int RB = (BN * BK) / (256 * 8);
    constexpr int KEEP = RA + RB;
    __shared__ __align__(16) short lA[3][BM * BK];
    __shared__ __align__(16) short lB[3][BN * BK];
    const int tid = threadIdx.x;
    const int lane = tid & 63, wid = tid >> 6;
    const int wm = (wid / WC) * (BM / WR);
    const int wn = (wid % WC) * (BN / WC);
    const int r16 = lane & 15, quad = lane >> 4;

    if (MODE == 4) {
        A  += (size_t)blockIdx.z * K;
        Bw += (size_t)blockIdx.z * K;
        o_f32 += (size_t)blockIdx.z * M * N;
    }

    int nx = gridDim.x;
    int bx = blockIdx.x, by = blockIdx.y;
    if ((nx & 7) == 0 && nx >= 8) {
        int bid = by * nx + bx;
        int xcd = bid & 7, idx = bid >> 3;
        int npx = nx >> 3;
        bx = xcd * npx + (idx % npx);
        by = idx / npx;
    }
    const int m0 = by * BM, n0 = bx * BN;

    floatx4 acc[FM][FN] = {};
    const int NT = K / BK;

#pragma unroll
    for (int r = 0; r < RA; ++r) {
        int idx = r * 256 + tid;
        int row = idx >> 2, kc = (idx & 3) << 3;
        async16(&A[(size_t)(m0 + row) * lda + kc], &lA[0][idx * 8]);
    }
#pragma unroll
    for (int r = 0; r < RB; ++r) {
        int idx = r * 256 + tid;
        int row = idx >> 2, kc = (idx & 3) << 3;
        async16(&Bw[(size_t)(n0 + row) * ldb + kc], &lB[0][idx * 8]);
    }
    if (NT > 1) {
#pragma unroll
        for (int r = 0; r < RA; ++r) {
            int idx = r * 256 + tid;
            int row = idx >> 2, kc = (idx & 3) << 3;
            async16(&A[(size_t)(m0 + row) * lda + BK + kc], &lA[1][idx * 8]);
        }
#pragma unroll
        for (int r = 0; r < RB; ++r) {
            int idx = r * 256 + tid;
            int row = idx >> 2, kc = (idx & 3) << 3;
            async16(&Bw[(size_t)(n0 + row) * ldb + BK + kc], &lB[1][idx * 8]);
        }
    }

    for (int t = 0; t < NT; ++t) {
        if (t > 0) __builtin_amdgcn_s_barrier();
        if (t + 2 < NT) {
            const int k2 = (t + 2) * BK;
            const int nb = (t + 2) % 3;
#pragma unroll
            for (int r = 0; r < RA; ++r) {
                int idx = r * 256 + tid;
                int row = idx >> 2, kc = (idx & 3) << 3;
                async16(&A[(size_t)(m0 + row) * lda + k2 + kc], &lA[nb][idx * 8]);
            }
#pragma unroll
            for (int r = 0; r < RB; ++r) {
                int idx = r * 256 + tid;
                int row = idx >> 2, kc = (idx & 3) << 3;
                async16(&Bw[(size_t)(n0 + row) * ldb + k2 + kc], &lB[nb][idx * 8]);
            }
            __builtin_amdgcn_s_waitcnt(0x0F70 | (2 * KEEP));
        } else if (t + 1 < NT) {
            __builtin_amdgcn_s_waitcnt(0x0F70 | KEEP);
        } else {
            __builtin_amdgcn_s_waitcnt(0x0F70);
        }
        __builtin_amdgcn_s_barrier();

        const int cb = t % 3;
        short8 af[FM], bfv[FN];
#pragma unroll
        for (int i = 0; i < FM; ++i)
            af[i] = *reinterpret_cast<const short8*>(&lA[cb][(wm + i * 16 + r16) * BK + quad * 8]);
#pragma unroll
        for (int j = 0; j < FN; ++j)
            bfv[j] = *reinterpret_cast<const short8*>(&lB[cb][(wn + j * 16 + r16) * BK + quad * 8]);
#pragma unroll
        for (int i = 0; i < FM; ++i)
#pragma unroll
            for (int j = 0; j < FN; ++j)
                acc[i][j] = __builtin_amdgcn_mfma_f32_16x16x32_bf16(af[i], bfv[j], acc[i][j], 0, 0, 0);
    }

    const float s = (MODE == 4) ? 1.0f : *s_ptr;
#pragma unroll
    for (int i = 0; i < FM; ++i) {
#pragma unroll
        for (int j = 0; j < FN; ++j) {
#pragma unroll
            for (int r = 0; r < 4; ++r) {
                int gr = m0 + wm + i * 16 + quad * 4 + r;
                int gc = n0 + wn + j * 16 + r16;
                float v = acc[i][j][r] * s;
                if (MODE == 1) {
                    o_bf16[(size_t)gr * N + gc] = __float2bfloat16(v);
                } else if (MODE == 2) {
                    float dt = v + bias[gc];
                    float dc = 0.5f + 0.5f * dt / (1.0f + fabsf(dt));
                    o_u16[(size_t)gr * N + gc] = (unsigned short)rintf(dc * 32768.0f);
                } else if (MODE == 3) {
                    o_f32[(size_t)gr * N + gc] = v + resid[(size_t)gr * N + gc];
                } else {
                    o_f32[(size_t)gr * N + gc] = v;
                }
            }
        }
    }
}

// ---------------- split-K reduce for GEMM2: dbl = bf16(s * sum_z part[z]) ----------------
__global__ __launch_bounds__(256) void k_red(const float* __restrict__ part,
                                             const float* __restrict__ s_ptr,
                                             __hip_bfloat16* __restrict__ dbl) {
    int i = blockIdx.x * 256 + threadIdx.x;  // < NR*DTR
    float s = *s_ptr;
    float acc = 0.f;
#pragma unroll
    for (int z = 0; z < KSLICE; ++z) acc += part[(size_t)z * NR * DTR + i];
    dbl[i] = __float2bfloat16(acc * s);
}

// ---------------- causal depthwise conv (k=4, bf16 in) + bias + squareplus ----------------
__global__ __launch_bounds__(256) void k_conv(const __hip_bfloat16* __restrict__ xc,
                                              const float* __restrict__ cw,
                                              const float* __restrict__ cb,
                                              __hip_bfloat16* __restrict__ xact) {
    int c = blockIdx.x * 256 + threadIdx.x;
    int t0 = blockIdx.y * CCONV;
    int b = blockIdx.z;
    float w0 = cw[c * 4 + 0], w1 = cw[c * 4 + 1], w2 = cw[c * 4 + 2], w3 = cw[c * 4 + 3];
    float bias = cb[c];
    const __hip_bfloat16* base = xc + (size_t)b * L_ * DI + c;
    float x3 = (t0 - 3 >= 0) ? __bfloat162float(base[(size_t)(t0 - 3) * DI]) : 0.f;
    float x2 = (t0 - 2 >= 0) ? __bfloat162float(base[(size_t)(t0 - 2) * DI]) : 0.f;
    float x1 = (t0 - 1 >= 0) ? __bfloat162float(base[(size_t)(t0 - 1) * DI]) : 0.f;
    for (int t = t0; t < t0 + CCONV; ++t) {
        float xt = __bfloat162float(base[(size_t)t * DI]);
        float y = x3 * w0 + x2 * w1 + x1 * w2 + xt * w3 + bias;
        xact[((size_t)(b * L_ + t)) * DI + c] = __float2bfloat16(squareplus_f(y));
        x3 = x2; x2 = x1; x1 = xt;
    }
}

// ---------------- chunked linear scan: pass1 (chunk aggregates) ----------------
__global__ __launch_bounds__(256) void k_scan1(const unsigned short* __restrict__ dk,
                                               const __hip_bfloat16* __restrict__ u,
                                               float* __restrict__ cA, float* __restrict__ cB) {
    int c = blockIdx.x * 256 + threadIdx.x;
    int j = blockIdx.y, b = blockIdx.z;
    size_t base = ((size_t)b * L_ + (size_t)j * CHUNK) * DI + c;
    float Ac = 1.f, Bc = 0.f;
    for (int t = 0; t < CHUNK; ++t) {
        float a = dk[base + (size_t)t * DI] * (1.0f / 32768.0f);
        float uv = __bfloat162float(u[base + (size_t)t * DI]);
        Bc = a * Bc + (1.f - a) * uv;
        Ac *= a;
    }
    size_t o = ((size_t)(b * NCHUNK + j)) * DI + c;
    cA[o] = Ac;
    cB[o] = Bc;
}

// ---------------- pass2: prefix (recomputed per block) + final scan + y = h*sp(z) ----------------
__global__ __launch_bounds__(256) void k_scan3(const unsigned short* __restrict__ dk,
                                               const __hip_bfloat16* __restrict__ u,
                                               const __hip_bfloat16* __restrict__ zraw,
                                               const float* __restrict__ cA,
                                               const float* __restrict__ cB,
                                               __hip_bfloat16* __restrict__ y) {
    int c = blockIdx.x * 256 + threadIdx.x;
    int j = blockIdx.y, b = blockIdx.z;
    float h = 0.f;
    for (int jj = 0; jj < j; ++jj) {
        size_t o = ((size_t)(b * NCHUNK + jj)) * DI + c;
        h = cA[o] * h + cB[o];
    }
    size_t base = ((size_t)b * L_ + (size_t)j * CHUNK) * DI + c;
    for (int t = 0; t < CHUNK; ++t) {
        float a = dk[base + (size_t)t * DI] * (1.0f / 32768.0f);
        float uv = __bfloat162float(u[base + (size_t)t * DI]);
        h = a * h + (1.f - a) * uv;
        float zv = squareplus_f(__bfloat162float(zraw[base + (size_t)t * DI]));
        y[base + (size_t)t * DI] = __float2bfloat16(h * zv);
    }
}

// ---------------- launch ----------------
extern "C" void kernel_launch(void* const* d_in, const int* in_sizes, int n_in,
                              void* d_out, int out_size, void* d_ws, size_t ws_size,
                              hipStream_t stream) {
    const float* x      = (const float*)d_in[0];
    const float* gamma  = (const float*)d_in[1];
    const float* step   = (const float*)d_in[2];
    const float* W_in   = (const float*)d_in[3];
    const float* conv_w = (const float*)d_in[4];
    const float* conv_b = (const float*)d_in[5];
    const float* W_x    = (const float*)d_in[6];
    const float* W_dt   = (const float*)d_in[7];
    const float* b_dt   = (const float*)d_in[8];
    const float* W_out  = (const float*)d_in[9];

    char* ws = (char*)d_ws;
    float*          scal = (float*)(ws + OFF_SCAL);
    float*          part = (float*)(ws + OFF_PART);
    signed char*    xn8  = (signed char*)(ws + OFF_XN);
    signed char*    Tin8 = (signed char*)(ws + OFF_TIN);
    __hip_bfloat16* Tx   = (__hip_bfloat16*)(ws + OFF_TX);
    __hip_bfloat16* Tdt  = (__hip_bfloat16*)(ws + OFF_TDT);
    __hip_bfloat16* Tout = (__hip_bfloat16*)(ws + OFF_TOUT);
    __hip_bfloat16* xcb  = (__hip_bfloat16*)(ws + OFF_XC);
    float*          p2   = (float*)(ws + OFF_P2);
    __hip_bfloat16* zraw = (__hip_bfloat16*)(ws + OFF_ZSP);
    __hip_bfloat16* xact = (__hip_bfloat16*)(ws + OFF_XACT);
    __hip_bfloat16* dbl  = (__hip_bfloat16*)(ws + OFF_DBL);
    unsigned short* dec  = (unsigned short*)(ws + OFF_DEC);
    float*          cA   = (float*)(ws + OFF_CA);
    float*          cB   = (float*)(ws + OFF_CB);
    __hip_bfloat16* yb   = (__hip_bfloat16*)(ws + OFF_Y);
    float*          srow = (float*)(ws + OFF_SROW);
    float*          out  = (float*)d_out;

    // weight scales + ternary quantization (fused, vectorized; W_in -> i8)
    k_abs_all<<<dim3(256, 4), 256, 0, stream>>>(W_in, W_x, W_dt, W_out, part);
    k_finalize<<<1, 256, 0, stream>>>(part, scal);
    k_quant_all<<<6400, 256, 0, stream>>>(W_in, W_x, W_dt, W_out, scal, Tin8, Tx, Tdt, Tout);

    // norm -> xn i8 + per-row scale
    k_norm<<<NR, 256, 0, stream>>>(x, gamma, step, xn8, srow);

    // GEMM1 (i8): xz = (xn8 @ Tin8^T) * sW * srow ; split -> xc bf16, z raw bf16
    k_gemm1_i8<<<dim3((2 * DI) / 128, NR / 128), 256, 0, stream>>>(
        xn8, Tin8, scal + 0, srow, xcb, zraw);

    // conv + bias + squareplus -> xact (bf16)
    k_conv<<<dim3(DI / 256, L_ / CCONV, B_), 256, 0, stream>>>(xcb, conv_w, conv_b, xact);

    // GEMM2 (split-K): p2[z] = xact[:, z*256:(z+1)*256] @ T_x[:64, ...]^T
    k_gemm<64, 64, 2, 2, 4><<<dim3(1, NR / 64, KSLICE), 256, 0, stream>>>(
        xact, Tx, NR, DTR, DI / KSLICE, DI, DI, nullptr, p2, nullptr, nullptr, nullptr, nullptr);
    k_red<<<(NR * DTR) / 256, 256, 0, stream>>>(p2, scal + 1, dbl);

    // GEMM3: dt = dbl @ T_dt^T * s + b_dt -> sigmoid -> dyadic u16 decay (64x128 tiles)
    k_gemm<64, 128, 2, 2, 2><<<dim3(DI / 128, NR / 64), 256, 0, stream>>>(
        dbl, Tdt, NR, DI, DTR, DTR, DTR, scal + 2, nullptr, nullptr, dec, b_dt, nullptr);

    // scan (2 passes, 64-step chunks), pass2 recomputes prefix + fuses y = h * squareplus(z)
    k_scan1<<<dim3(DI / 256, NCHUNK, B_), 256, 0, stream>>>(dec, xact, cA, cB);
    k_scan3<<<dim3(DI / 256, NCHUNK, B_), 256, 0, stream>>>(dec, xact, zraw, cA, cB, yb);

    // GEMM4: out = y @ T_out^T * s + residual  (BM=64/BN=128 -> 1024 blocks)
    k_gemm<64, 128, 2, 2, 3><<<dim3(DM / 128, NR / 64), 256, 0, stream>>>(
        yb, Tout, NR, DM, DI, DI, DI, scal + 3, out, nullptr, nullptr, nullptr, x);

    (void)in_sizes; (void)n_in; (void)out_size; (void)ws_size;
}